// Round 1
// baseline (1159.186 us; speedup 1.0000x reference)
//
#include <hip/hip_runtime.h>
#include <hip/hip_bf16.h>
#include <math.h>

// ChunkedLinearCrossEntropyLoss fused kernel for MI355X (gfx950)
//
// Problem: hidden[4096,2048] f32, weight[32768,2048] f32, targets[4096] i32
// loss = mean_valid(0.9*(lse - x_t) + 0.1*(lse - mean_logits)) + 1e-4*mean_valid(lse^2)
// logits softcapped: 20*tanh(l/20)
//
// Plan:
//  K0 target_logit : x_t[row] = softcap(h[row]. w[tgt[row]]) in fp32
//  K1 gemm_partial : bf16 MFMA 128x128 tile -> per-row (max, sumexp, sumlogit)
//                    partial per column-block, written to ws
//  K2 row_reduce   : merge 256 partials per row -> row_loss, lse^2, valid
//  K3 final_reduce : scalar loss -> d_out[0]
//
// ws layout: [0, 16MB)            float4 part[4096][256]  (m, s, t, pad)
//            [16MB, +16KB)        float  xt[4096]
//            [.., +48KB)          float  rowbuf[4096][3]

#define N_ROWS 4096
#define DIM    2048
#define VOCAB  32768
#define BM 128
#define BN 128
#define BK 32
#define NCB (VOCAB / BN)          // 256 column blocks
#define ROW_TILES (N_ROWS / BM)   // 32
#define IGNORE_IDX (-100)

typedef short s16x8 __attribute__((ext_vector_type(8)));
typedef unsigned short u16x8 __attribute__((ext_vector_type(8)));
typedef float f32x4 __attribute__((ext_vector_type(4)));

__device__ __forceinline__ float softcap(float x) {
    return 20.0f * tanhf(x * 0.05f);
}

// f32 -> bf16 round-to-nearest-even
__device__ __forceinline__ unsigned short f2bf(float f) {
    union { float f; unsigned u; } v; v.f = f;
    unsigned r = v.u + 0x7FFFu + ((v.u >> 16) & 1u);
    return (unsigned short)(r >> 16);
}

// ---------------------------------------------------------------------------
// K0: x_t[row] = softcap(dot(hidden[row], weight[tgt])) in fp32. 1 wave/row.
// ---------------------------------------------------------------------------
__global__ __launch_bounds__(256) void target_logit(
    const float* __restrict__ hidden, const float* __restrict__ weight,
    const int* __restrict__ targets, float* __restrict__ xtbuf)
{
    int row  = blockIdx.x * 4 + (threadIdx.x >> 6);
    int lane = threadIdx.x & 63;
    if (row >= N_ROWS) return;
    int tgt = targets[row];
    if (tgt < 0 || tgt >= VOCAB) {              // covers IGNORE_IDX
        if (lane == 0) xtbuf[row] = 0.f;
        return;
    }
    const float4* h4 = (const float4*)(hidden + (size_t)row * DIM);
    const float4* w4 = (const float4*)(weight + (size_t)tgt * DIM);
    float d = 0.f;
#pragma unroll
    for (int j = 0; j < DIM / 4 / 64; j++) {    // 8 iters
        float4 a = h4[lane + 64 * j];
        float4 b = w4[lane + 64 * j];
        d += a.x * b.x + a.y * b.y + a.z * b.z + a.w * b.w;
    }
#pragma unroll
    for (int off = 1; off < 64; off <<= 1) d += __shfl_xor(d, off, 64);
    if (lane == 0) xtbuf[row] = softcap(d);
}

// ---------------------------------------------------------------------------
// K1: 128x128 logit tile via bf16 MFMA, fused softcap + per-row partials.
// 4 waves in 2x2; wave computes 64x64 via 4x4 fragments of 16x16x32.
// ---------------------------------------------------------------------------
__global__ __launch_bounds__(256) void gemm_partial(
    const float* __restrict__ hidden, const float* __restrict__ weight,
    float4* __restrict__ part)
{
    __shared__ unsigned short sA[BM * BK];   // [row][k] row-major, 8 KB
    __shared__ unsigned short sB[BN * BK];   // [vocab][k] row-major, 8 KB
    __shared__ float red[4][64][3];          // per-wave per-row partials

    const int bid  = blockIdx.x;
    const int brow = bid & (ROW_TILES - 1);  // consecutive blocks share weight tile
    const int bcol = bid >> 5;
    const int t    = threadIdx.x;
    const int lane = t & 63;
    const int w    = t >> 6;
    const int wr   = w >> 1, wc = w & 1;

    // staging: thread t loads 16 f32 (row t>>1, cols (t&1)*16..+15)
    const int srow = t >> 1;
    const int scol = (t & 1) * 16;
    const float* gA = hidden + (size_t)(brow * BM + srow) * DIM + scol;
    const float* gB = weight + (size_t)(bcol * BN + srow) * DIM + scol;
    unsigned short* wA = &sA[srow * BK + scol];
    unsigned short* wB = &sB[srow * BK + scol];

    f32x4 acc[4][4];
#pragma unroll
    for (int m = 0; m < 4; m++)
#pragma unroll
        for (int n = 0; n < 4; n++) acc[m][n] = (f32x4){0.f, 0.f, 0.f, 0.f};

    const unsigned short* pa = &sA[(wr * 64 + (lane & 15)) * BK + (lane >> 4) * 8];
    const unsigned short* pb = &sB[(wc * 64 + (lane & 15)) * BK + (lane >> 4) * 8];

    for (int k0 = 0; k0 < DIM; k0 += BK) {
        float4 a0 = *(const float4*)(gA + k0);
        float4 a1 = *(const float4*)(gA + k0 + 4);
        float4 a2 = *(const float4*)(gA + k0 + 8);
        float4 a3 = *(const float4*)(gA + k0 + 12);
        float4 b0 = *(const float4*)(gB + k0);
        float4 b1 = *(const float4*)(gB + k0 + 4);
        float4 b2 = *(const float4*)(gB + k0 + 8);
        float4 b3 = *(const float4*)(gB + k0 + 12);
        __syncthreads();   // previous iteration's LDS reads complete
        u16x8 pa0 = { f2bf(a0.x), f2bf(a0.y), f2bf(a0.z), f2bf(a0.w),
                      f2bf(a1.x), f2bf(a1.y), f2bf(a1.z), f2bf(a1.w) };
        u16x8 pa1 = { f2bf(a2.x), f2bf(a2.y), f2bf(a2.z), f2bf(a2.w),
                      f2bf(a3.x), f2bf(a3.y), f2bf(a3.z), f2bf(a3.w) };
        u16x8 pb0 = { f2bf(b0.x), f2bf(b0.y), f2bf(b0.z), f2bf(b0.w),
                      f2bf(b1.x), f2bf(b1.y), f2bf(b1.z), f2bf(b1.w) };
        u16x8 pb1 = { f2bf(b2.x), f2bf(b2.y), f2bf(b2.z), f2bf(b2.w),
                      f2bf(b3.x), f2bf(b3.y), f2bf(b3.z), f2bf(b3.w) };
        *(u16x8*)wA = pa0;
        *(u16x8*)(wA + 8) = pa1;
        *(u16x8*)wB = pb0;
        *(u16x8*)(wB + 8) = pb1;
        __syncthreads();

        s16x8 afr[4], bfr[4];
#pragma unroll
        for (int m = 0; m < 4; m++) afr[m] = *(const s16x8*)(pa + m * 16 * BK);
#pragma unroll
        for (int n = 0; n < 4; n++) bfr[n] = *(const s16x8*)(pb + n * 16 * BK);
#pragma unroll
        for (int m = 0; m < 4; m++)
#pragma unroll
            for (int n = 0; n < 4; n++)
                acc[m][n] = __builtin_amdgcn_mfma_f32_16x16x32_bf16(
                    afr[m], bfr[n], acc[m][n], 0, 0, 0);
    }

    // --- fused per-row reduction over this tile's 128 columns ---
    // C/D layout: col = lane&15 (+16*n), row = (lane>>4)*4 + reg (+16*m)
    const int g  = lane >> 4;
    const int li = lane & 15;
#pragma unroll
    for (int m = 0; m < 4; m++) {
#pragma unroll
        for (int r = 0; r < 4; r++) {
            float s0 = softcap(acc[m][0][r]);
            float s1 = softcap(acc[m][1][r]);
            float s2 = softcap(acc[m][2][r]);
            float s3 = softcap(acc[m][3][r]);
            float mx = fmaxf(fmaxf(s0, s1), fmaxf(s2, s3));
#pragma unroll
            for (int off = 1; off < 16; off <<= 1)
                mx = fmaxf(mx, __shfl_xor(mx, off, 64));
            float se = __expf(s0 - mx) + __expf(s1 - mx) +
                       __expf(s2 - mx) + __expf(s3 - mx);
            float st = s0 + s1 + s2 + s3;
#pragma unroll
            for (int off = 1; off < 16; off <<= 1) {
                se += __shfl_xor(se, off, 64);
                st += __shfl_xor(st, off, 64);
            }
            if (li == 0) {
                int rl = m * 16 + g * 4 + r;   // row within wave's 64
                red[w][rl][0] = mx;
                red[w][rl][1] = se;
                red[w][rl][2] = st;
            }
        }
    }
    __syncthreads();
    if (t < BM) {
        int r  = t;
        int wa = (r >> 6) * 2;     // waves wa (cols 0-63) and wa+1 (cols 64-127)
        int rr = r & 63;
        float m1 = red[wa][rr][0],     e1 = red[wa][rr][1],     t1 = red[wa][rr][2];
        float m2 = red[wa + 1][rr][0], e2 = red[wa + 1][rr][1], t2 = red[wa + 1][rr][2];
        float mm = fmaxf(m1, m2);
        float ss = e1 * __expf(m1 - mm) + e2 * __expf(m2 - mm);
        float tt = t1 + t2;
        part[(size_t)(brow * BM + r) * NCB + bcol] = make_float4(mm, ss, tt, 0.f);
    }
}

// ---------------------------------------------------------------------------
// K2: merge the 256 column-block partials per row. 1 wave/row.
// ---------------------------------------------------------------------------
__global__ __launch_bounds__(256) void row_reduce(
    const float4* __restrict__ part, const int* __restrict__ targets,
    const float* __restrict__ xtbuf, float* __restrict__ rowbuf)
{
    int row  = blockIdx.x * 4 + (threadIdx.x >> 6);
    int lane = threadIdx.x & 63;
    if (row >= N_ROWS) return;
    const float4* p = part + (size_t)row * NCB;
    float4 v = p[lane];
    float m = v.x, s = v.y, st = v.z;
#pragma unroll
    for (int q = 1; q < NCB / 64; q++) {
        float4 u = p[lane + 64 * q];
        float mm = fmaxf(m, u.x);
        s = s * __expf(m - mm) + u.y * __expf(u.x - mm);
        m = mm;
        st += u.z;
    }
#pragma unroll
    for (int off = 1; off < 64; off <<= 1) {
        float om = __shfl_xor(m, off, 64);
        float os = __shfl_xor(s, off, 64);
        float ot = __shfl_xor(st, off, 64);
        float mm = fmaxf(m, om);
        s = s * __expf(m - mm) + os * __expf(om - mm);
        m = mm;
        st += ot;
    }
    if (lane == 0) {
        float lse = m + logf(s);
        int   tgt = targets[row];
        float vf  = (tgt != IGNORE_IDX) ? 1.f : 0.f;
        float xt  = xtbuf[row];
        float nll = lse - xt;
        float smooth = lse - st * (1.f / (float)VOCAB);
        float rl = 0.9f * nll + 0.1f * smooth;
        rowbuf[row * 3 + 0] = rl * vf;
        rowbuf[row * 3 + 1] = lse * lse * vf;
        rowbuf[row * 3 + 2] = vf;
    }
}

// ---------------------------------------------------------------------------
// K3: deterministic final reduction -> scalar loss.
// ---------------------------------------------------------------------------
__global__ __launch_bounds__(256) void final_reduce(
    const float* __restrict__ rowbuf, float* __restrict__ out)
{
    __shared__ float sl[256], sz[256], sv[256];
    int t = threadIdx.x;
    float ls = 0.f, zs = 0.f, vs = 0.f;
    for (int r = t; r < N_ROWS; r += 256) {
        ls += rowbuf[r * 3 + 0];
        zs += rowbuf[r * 3 + 1];
        vs += rowbuf[r * 3 + 2];
    }
    sl[t] = ls; sz[t] = zs; sv[t] = vs;
    __syncthreads();
    for (int o = 128; o > 0; o >>= 1) {
        if (t < o) { sl[t] += sl[t + o]; sz[t] += sz[t + o]; sv[t] += sv[t + o]; }
        __syncthreads();
    }
    if (t == 0) {
        float nv = fmaxf(sv[0], 1.f);
        out[0] = sl[0] / nv + 1e-4f * (sz[0] / nv);
    }
}

// ---------------------------------------------------------------------------
extern "C" void kernel_launch(void* const* d_in, const int* in_sizes, int n_in,
                              void* d_out, int out_size, void* d_ws, size_t ws_size,
                              hipStream_t stream)
{
    const float* hidden  = (const float*)d_in[0];
    const float* weight  = (const float*)d_in[1];
    const int*   targets = (const int*)d_in[2];
    float*       out     = (float*)d_out;

    char*   ws     = (char*)d_ws;
    float4* part   = (float4*)ws;                                   // 16 MB
    float*  xtbuf  = (float*)(ws + (size_t)N_ROWS * NCB * sizeof(float4));
    float*  rowbuf = xtbuf + N_ROWS;

    target_logit<<<N_ROWS / 4, 256, 0, stream>>>(hidden, weight, targets, xtbuf);
    gemm_partial<<<ROW_TILES * NCB, 256, 0, stream>>>(hidden, weight, part);
    row_reduce<<<N_ROWS / 4, 256, 0, stream>>>(part, targets, xtbuf, rowbuf);
    final_reduce<<<1, 256, 0, stream>>>(rowbuf, out);
}

// Round 2
// 776.769 us; speedup vs baseline: 1.4923x; 1.4923x over previous
//
#include <hip/hip_runtime.h>
#include <hip/hip_bf16.h>
#include <math.h>

// ChunkedLinearCrossEntropyLoss fused kernel for MI355X (gfx950)  — R2
//
// hidden[4096,2048] f32, weight[32768,2048] f32, targets[4096] i32 -> scalar
//
//  Kc  convert_bf16  : f32 -> bf16 copies of hidden and weight in ws
//  K0  target_logit  : x_t[row] = softcap(h[row].w[tgt[row]]) in fp32
//  K1  gemm_partial_bf16 : m97-structure 128x128 bf16 MFMA tile with
//       global_load_lds(16B) staging; fused softcap + per-row partials
//  K2  row_reduce    : merge 256 column-block partials per row
//  K3  final_reduce  : scalar loss
//
// ws layout (aligned, ~160.1 MiB):
//   part   float4[4096][256]   16 MB
//   xt     float [4096]
//   rowbuf float [4096][3]
//   hidB   bf16  [4096][2048]  16 MB
//   wgtB   bf16  [32768][2048] 134 MB
// Falls back to the R1 all-in-one kernel if ws_size is too small.

#define N_ROWS 4096
#define DIM    2048
#define VOCAB  32768
#define BM 128
#define BN 128
#define BK 32
#define NCB (VOCAB / BN)          // 256 column blocks
#define ROW_TILES (N_ROWS / BM)   // 32
#define IGNORE_IDX (-100)

typedef short s16x8 __attribute__((ext_vector_type(8)));
typedef unsigned short u16x8 __attribute__((ext_vector_type(8)));
typedef float f32x4 __attribute__((ext_vector_type(4)));

#define AS3(p) ((__attribute__((address_space(3))) void*)(p))
#define AS1(p) ((const __attribute__((address_space(1))) void*)(p))

__device__ __forceinline__ float softcap(float x) {
    return 20.0f * tanhf(x * 0.05f);
}

// f32 -> bf16 round-to-nearest-even
__device__ __forceinline__ unsigned short f2bf(float f) {
    union { float f; unsigned u; } v; v.f = f;
    unsigned r = v.u + 0x7FFFu + ((v.u >> 16) & 1u);
    return (unsigned short)(r >> 16);
}

// ---------------------------------------------------------------------------
// Kc: vectorized f32 -> bf16 conversion (memory-bound)
// ---------------------------------------------------------------------------
__global__ __launch_bounds__(256) void convert_bf16(
    const float* __restrict__ src, unsigned short* __restrict__ dst, int nvec8)
{
    int idx = blockIdx.x * 256 + threadIdx.x;
    int stride = gridDim.x * 256;
    for (int i = idx; i < nvec8; i += stride) {
        const float4* s = (const float4*)(src + (size_t)i * 8);
        float4 a = s[0], b = s[1];
        u16x8 v = { f2bf(a.x), f2bf(a.y), f2bf(a.z), f2bf(a.w),
                    f2bf(b.x), f2bf(b.y), f2bf(b.z), f2bf(b.w) };
        *(u16x8*)(dst + (size_t)i * 8) = v;
    }
}

// ---------------------------------------------------------------------------
// K0: x_t[row] = softcap(dot(hidden[row], weight[tgt])) in fp32. 1 wave/row.
// ---------------------------------------------------------------------------
__global__ __launch_bounds__(256) void target_logit(
    const float* __restrict__ hidden, const float* __restrict__ weight,
    const int* __restrict__ targets, float* __restrict__ xtbuf)
{
    int row  = blockIdx.x * 4 + (threadIdx.x >> 6);
    int lane = threadIdx.x & 63;
    if (row >= N_ROWS) return;
    int tgt = targets[row];
    if (tgt < 0 || tgt >= VOCAB) {              // covers IGNORE_IDX
        if (lane == 0) xtbuf[row] = 0.f;
        return;
    }
    const float4* h4 = (const float4*)(hidden + (size_t)row * DIM);
    const float4* w4 = (const float4*)(weight + (size_t)tgt * DIM);
    float d = 0.f;
#pragma unroll
    for (int j = 0; j < DIM / 4 / 64; j++) {    // 8 iters
        float4 a = h4[lane + 64 * j];
        float4 b = w4[lane + 64 * j];
        d += a.x * b.x + a.y * b.y + a.z * b.z + a.w * b.w;
    }
#pragma unroll
    for (int off = 1; off < 64; off <<= 1) d += __shfl_xor(d, off, 64);
    if (lane == 0) xtbuf[row] = softcap(d);
}

// ---------------------------------------------------------------------------
// K1 (fast path): m97-structure bf16 GEMM, global_load_lds staging.
// 4 waves 2x2; wave computes 64x64 via 4x4 fragments of 16x16x32.
// LDS tiles are LINEAR [row][k] (global_load_lds writes base + lane*16).
// ---------------------------------------------------------------------------
__global__ __launch_bounds__(256) void gemm_partial_bf16(
    const unsigned short* __restrict__ A, const unsigned short* __restrict__ B,
    float4* __restrict__ part)
{
    __shared__ unsigned short sA[BM * BK];   // 8 KB, [row][k] row-major
    __shared__ unsigned short sB[BN * BK];   // 8 KB
    __shared__ float red[4][64][3];

    const int bid  = blockIdx.x;
    const int brow = bid & (ROW_TILES - 1);  // consecutive blocks share weight tile
    const int bcol = bid >> 5;
    const int t    = threadIdx.x;
    const int lane = t & 63;
    const int w    = t >> 6;
    const int wr   = w >> 1, wc = w & 1;

    // Staging: per wave, 2 calls for A + 2 for B. Call r (r=0,1):
    //   LDS byte base (w*2+r)*1024; HW writes lane i at base + i*16
    //   -> element row (w*2+r)*16 + (lane>>2), col (lane&3)*8
    const int srow = lane >> 2;
    const int scol = (lane & 3) * 8;
    const unsigned short* gA0 = A + (size_t)(brow * BM + w * 32 + srow) * DIM + scol;
    const unsigned short* gA1 = gA0 + (size_t)16 * DIM;
    const unsigned short* gB0 = B + (size_t)(bcol * BN + w * 32 + srow) * DIM + scol;
    const unsigned short* gB1 = gB0 + (size_t)16 * DIM;
    unsigned short* lA = &sA[w * 1024];      // (w*2+0)*512 elements
    unsigned short* lB = &sB[w * 1024];

    f32x4 acc[4][4];
#pragma unroll
    for (int m = 0; m < 4; m++)
#pragma unroll
        for (int n = 0; n < 4; n++) acc[m][n] = (f32x4){0.f, 0.f, 0.f, 0.f};

    const unsigned short* pa = &sA[(wr * 64 + (lane & 15)) * BK + (lane >> 4) * 8];
    const unsigned short* pb = &sB[(wc * 64 + (lane & 15)) * BK + (lane >> 4) * 8];

    for (int k0 = 0; k0 < DIM; k0 += BK) {
        __syncthreads();   // all waves done reading LDS from previous step
        __builtin_amdgcn_global_load_lds(AS1(gA0 + k0), AS3(lA),       16, 0, 0);
        __builtin_amdgcn_global_load_lds(AS1(gA1 + k0), AS3(lA + 512), 16, 0, 0);
        __builtin_amdgcn_global_load_lds(AS1(gB0 + k0), AS3(lB),       16, 0, 0);
        __builtin_amdgcn_global_load_lds(AS1(gB1 + k0), AS3(lB + 512), 16, 0, 0);
        __syncthreads();   // compiler drains vmcnt(0) before s_barrier

        s16x8 afr[4], bfr[4];
#pragma unroll
        for (int m = 0; m < 4; m++) afr[m] = *(const s16x8*)(pa + m * 16 * BK);
#pragma unroll
        for (int n = 0; n < 4; n++) bfr[n] = *(const s16x8*)(pb + n * 16 * BK);
#pragma unroll
        for (int m = 0; m < 4; m++)
#pragma unroll
            for (int n = 0; n < 4; n++)
                acc[m][n] = __builtin_amdgcn_mfma_f32_16x16x32_bf16(
                    afr[m], bfr[n], acc[m][n], 0, 0, 0);
    }

    // --- fused per-row reduction over this tile's 128 columns ---
    // C/D layout: col = lane&15 (+16*n), row = (lane>>4)*4 + reg (+16*m)
    const int g  = lane >> 4;
    const int li = lane & 15;
#pragma unroll
    for (int m = 0; m < 4; m++) {
#pragma unroll
        for (int r = 0; r < 4; r++) {
            float s0 = softcap(acc[m][0][r]);
            float s1 = softcap(acc[m][1][r]);
            float s2 = softcap(acc[m][2][r]);
            float s3 = softcap(acc[m][3][r]);
            float mx = fmaxf(fmaxf(s0, s1), fmaxf(s2, s3));
#pragma unroll
            for (int off = 1; off < 16; off <<= 1)
                mx = fmaxf(mx, __shfl_xor(mx, off, 64));
            float se = __expf(s0 - mx) + __expf(s1 - mx) +
                       __expf(s2 - mx) + __expf(s3 - mx);
            float st = s0 + s1 + s2 + s3;
#pragma unroll
            for (int off = 1; off < 16; off <<= 1) {
                se += __shfl_xor(se, off, 64);
                st += __shfl_xor(st, off, 64);
            }
            if (li == 0) {
                int rl = m * 16 + g * 4 + r;
                red[w][rl][0] = mx;
                red[w][rl][1] = se;
                red[w][rl][2] = st;
            }
        }
    }
    __syncthreads();
    if (t < BM) {
        int r  = t;
        int wa = (r >> 6) * 2;
        int rr = r & 63;
        float m1 = red[wa][rr][0],     e1 = red[wa][rr][1],     t1 = red[wa][rr][2];
        float m2 = red[wa + 1][rr][0], e2 = red[wa + 1][rr][1], t2 = red[wa + 1][rr][2];
        float mm = fmaxf(m1, m2);
        float ss = e1 * __expf(m1 - mm) + e2 * __expf(m2 - mm);
        float tt = t1 + t2;
        part[(size_t)(brow * BM + r) * NCB + bcol] = make_float4(mm, ss, tt, 0.f);
    }
}

// ---------------------------------------------------------------------------
// K1 (fallback, R1 version): in-loop f32->bf16 conversion, reg-staged.
// Used only if ws_size can't hold the bf16 copies.
// ---------------------------------------------------------------------------
__global__ __launch_bounds__(256) void gemm_partial_f32(
    const float* __restrict__ hidden, const float* __restrict__ weight,
    float4* __restrict__ part)
{
    __shared__ unsigned short sA[BM * BK];
    __shared__ unsigned short sB[BN * BK];
    __shared__ float red[4][64][3];

    const int bid  = blockIdx.x;
    const int brow = bid & (ROW_TILES - 1);
    const int bcol = bid >> 5;
    const int t    = threadIdx.x;
    const int lane = t & 63;
    const int w    = t >> 6;
    const int wr   = w >> 1, wc = w & 1;

    const int srow = t >> 1;
    const int scol = (t & 1) * 16;
    const float* gA = hidden + (size_t)(brow * BM + srow) * DIM + scol;
    const float* gB = weight + (size_t)(bcol * BN + srow) * DIM + scol;
    unsigned short* wA = &sA[srow * BK + scol];
    unsigned short* wB = &sB[srow * BK + scol];

    f32x4 acc[4][4];
#pragma unroll
    for (int m = 0; m < 4; m++)
#pragma unroll
        for (int n = 0; n < 4; n++) acc[m][n] = (f32x4){0.f, 0.f, 0.f, 0.f};

    const unsigned short* pa = &sA[(wr * 64 + (lane & 15)) * BK + (lane >> 4) * 8];
    const unsigned short* pb = &sB[(wc * 64 + (lane & 15)) * BK + (lane >> 4) * 8];

    for (int k0 = 0; k0 < DIM; k0 += BK) {
        float4 a0 = *(const float4*)(gA + k0);
        float4 a1 = *(const float4*)(gA + k0 + 4);
        float4 a2 = *(const float4*)(gA + k0 + 8);
        float4 a3 = *(const float4*)(gA + k0 + 12);
        float4 b0 = *(const float4*)(gB + k0);
        float4 b1 = *(const float4*)(gB + k0 + 4);
        float4 b2 = *(const float4*)(gB + k0 + 8);
        float4 b3 = *(const float4*)(gB + k0 + 12);
        __syncthreads();
        u16x8 pa0 = { f2bf(a0.x), f2bf(a0.y), f2bf(a0.z), f2bf(a0.w),
                      f2bf(a1.x), f2bf(a1.y), f2bf(a1.z), f2bf(a1.w) };
        u16x8 pa1 = { f2bf(a2.x), f2bf(a2.y), f2bf(a2.z), f2bf(a2.w),
                      f2bf(a3.x), f2bf(a3.y), f2bf(a3.z), f2bf(a3.w) };
        u16x8 pb0 = { f2bf(b0.x), f2bf(b0.y), f2bf(b0.z), f2bf(b0.w),
                      f2bf(b1.x), f2bf(b1.y), f2bf(b1.z), f2bf(b1.w) };
        u16x8 pb1 = { f2bf(b2.x), f2bf(b2.y), f2bf(b2.z), f2bf(b2.w),
                      f2bf(b3.x), f2bf(b3.y), f2bf(b3.z), f2bf(b3.w) };
        *(u16x8*)wA = pa0;
        *(u16x8*)(wA + 8) = pa1;
        *(u16x8*)wB = pb0;
        *(u16x8*)(wB + 8) = pb1;
        __syncthreads();

        s16x8 afr[4], bfr[4];
#pragma unroll
        for (int m = 0; m < 4; m++) afr[m] = *(const s16x8*)(pa + m * 16 * BK);
#pragma unroll
        for (int n = 0; n < 4; n++) bfr[n] = *(const s16x8*)(pb + n * 16 * BK);
#pragma unroll
        for (int m = 0; m < 4; m++)
#pragma unroll
            for (int n = 0; n < 4; n++)
                acc[m][n] = __builtin_amdgcn_mfma_f32_16x16x32_bf16(
                    afr[m], bfr[n], acc[m][n], 0, 0, 0);
    }

    const int g  = lane >> 4;
    const int li = lane & 15;
#pragma unroll
    for (int m = 0; m < 4; m++) {
#pragma unroll
        for (int r = 0; r < 4; r++) {
            float s0 = softcap(acc[m][0][r]);
            float s1 = softcap(acc[m][1][r]);
            float s2 = softcap(acc[m][2][r]);
            float s3 = softcap(acc[m][3][r]);
            float mx = fmaxf(fmaxf(s0, s1), fmaxf(s2, s3));
#pragma unroll
            for (int off = 1; off < 16; off <<= 1)
                mx = fmaxf(mx, __shfl_xor(mx, off, 64));
            float se = __expf(s0 - mx) + __expf(s1 - mx) +
                       __expf(s2 - mx) + __expf(s3 - mx);
            float st = s0 + s1 + s2 + s3;
#pragma unroll
            for (int off = 1; off < 16; off <<= 1) {
                se += __shfl_xor(se, off, 64);
                st += __shfl_xor(st, off, 64);
            }
            if (li == 0) {
                int rl = m * 16 + g * 4 + r;
                red[w][rl][0] = mx;
                red[w][rl][1] = se;
                red[w][rl][2] = st;
            }
        }
    }
    __syncthreads();
    if (t < BM) {
        int r  = t;
        int wa = (r >> 6) * 2;
        int rr = r & 63;
        float m1 = red[wa][rr][0],     e1 = red[wa][rr][1],     t1 = red[wa][rr][2];
        float m2 = red[wa + 1][rr][0], e2 = red[wa + 1][rr][1], t2 = red[wa + 1][rr][2];
        float mm = fmaxf(m1, m2);
        float ss = e1 * __expf(m1 - mm) + e2 * __expf(m2 - mm);
        float tt = t1 + t2;
        part[(size_t)(brow * BM + r) * NCB + bcol] = make_float4(mm, ss, tt, 0.f);
    }
}

// ---------------------------------------------------------------------------
// K2: merge the 256 column-block partials per row. 1 wave/row.
// ---------------------------------------------------------------------------
__global__ __launch_bounds__(256) void row_reduce(
    const float4* __restrict__ part, const int* __restrict__ targets,
    const float* __restrict__ xtbuf, float* __restrict__ rowbuf)
{
    int row  = blockIdx.x * 4 + (threadIdx.x >> 6);
    int lane = threadIdx.x & 63;
    if (row >= N_ROWS) return;
    const float4* p = part + (size_t)row * NCB;
    float4 v = p[lane];
    float m = v.x, s = v.y, st = v.z;
#pragma unroll
    for (int q = 1; q < NCB / 64; q++) {
        float4 u = p[lane + 64 * q];
        float mm = fmaxf(m, u.x);
        s = s * __expf(m - mm) + u.y * __expf(u.x - mm);
        m = mm;
        st += u.z;
    }
#pragma unroll
    for (int off = 1; off < 64; off <<= 1) {
        float om = __shfl_xor(m, off, 64);
        float os = __shfl_xor(s, off, 64);
        float ot = __shfl_xor(st, off, 64);
        float mm = fmaxf(m, om);
        s = s * __expf(m - mm) + os * __expf(om - mm);
        m = mm;
        st += ot;
    }
    if (lane == 0) {
        float lse = m + logf(s);
        int   tgt = targets[row];
        float vf  = (tgt != IGNORE_IDX) ? 1.f : 0.f;
        float xt  = xtbuf[row];
        float nll = lse - xt;
        float smooth = lse - st * (1.f / (float)VOCAB);
        float rl = 0.9f * nll + 0.1f * smooth;
        rowbuf[row * 3 + 0] = rl * vf;
        rowbuf[row * 3 + 1] = lse * lse * vf;
        rowbuf[row * 3 + 2] = vf;
    }
}

// ---------------------------------------------------------------------------
// K3: deterministic final reduction -> scalar loss.
// ---------------------------------------------------------------------------
__global__ __launch_bounds__(256) void final_reduce(
    const float* __restrict__ rowbuf, float* __restrict__ out)
{
    __shared__ float sl[256], sz[256], sv[256];
    int t = threadIdx.x;
    float ls = 0.f, zs = 0.f, vs = 0.f;
    for (int r = t; r < N_ROWS; r += 256) {
        ls += rowbuf[r * 3 + 0];
        zs += rowbuf[r * 3 + 1];
        vs += rowbuf[r * 3 + 2];
    }
    sl[t] = ls; sz[t] = zs; sv[t] = vs;
    __syncthreads();
    for (int o = 128; o > 0; o >>= 1) {
        if (t < o) { sl[t] += sl[t + o]; sz[t] += sz[t + o]; sv[t] += sv[t + o]; }
        __syncthreads();
    }
    if (t == 0) {
        float nv = fmaxf(sv[0], 1.f);
        out[0] = sl[0] / nv + 1e-4f * (sz[0] / nv);
    }
}

// ---------------------------------------------------------------------------
extern "C" void kernel_launch(void* const* d_in, const int* in_sizes, int n_in,
                              void* d_out, int out_size, void* d_ws, size_t ws_size,
                              hipStream_t stream)
{
    const float* hidden  = (const float*)d_in[0];
    const float* weight  = (const float*)d_in[1];
    const int*   targets = (const int*)d_in[2];
    float*       out     = (float*)d_out;

    char* ws = (char*)d_ws;
    size_t off = 0;
    float4* part = (float4*)(ws + off);
    off += (size_t)N_ROWS * NCB * sizeof(float4);           // 16 MB
    float* xtbuf = (float*)(ws + off);
    off += (size_t)N_ROWS * sizeof(float);
    float* rowbuf = (float*)(ws + off);
    off += (size_t)N_ROWS * 3 * sizeof(float);
    off = (off + 255) & ~(size_t)255;
    unsigned short* hidB = (unsigned short*)(ws + off);
    off += (size_t)N_ROWS * DIM * sizeof(unsigned short);   // 16 MB
    unsigned short* wgtB = (unsigned short*)(ws + off);
    off += (size_t)VOCAB * DIM * sizeof(unsigned short);    // 134 MB

    target_logit<<<N_ROWS / 4, 256, 0, stream>>>(hidden, weight, targets, xtbuf);

    if (ws_size >= off) {
        convert_bf16<<<2048, 256, 0, stream>>>(hidden, hidB, N_ROWS * DIM / 8);
        convert_bf16<<<2048, 256, 0, stream>>>(weight, wgtB, VOCAB * DIM / 8);
        gemm_partial_bf16<<<ROW_TILES * NCB, 256, 0, stream>>>(hidB, wgtB, part);
    } else {
        gemm_partial_f32<<<ROW_TILES * NCB, 256, 0, stream>>>(hidden, weight, part);
    }

    row_reduce<<<N_ROWS / 4, 256, 0, stream>>>(part, targets, xtbuf, rowbuf);
    final_reduce<<<1, 256, 0, stream>>>(rowbuf, out);
}

// Round 3
// 653.371 us; speedup vs baseline: 1.7742x; 1.1889x over previous
//
#include <hip/hip_runtime.h>
#include <hip/hip_bf16.h>
#include <math.h>

// ChunkedLinearCrossEntropyLoss fused kernel for MI355X (gfx950) — R3
//
// hidden[4096,2048] f32, weight[32768,2048] f32, targets[4096] i32 -> scalar
//
//  Kc  convert_bf16      : f32 -> bf16 copies of hidden and weight in ws
//  K0  target_logit      : x_t[row] = softcap(h[row].w[tgt[row]]) fp32
//  K1  gemm8ph           : 256x256 tile, BK=64, 8 waves, 4-phase/K-tile deep
//                          pipeline (counted vmcnt, T2 swizzle, setprio),
//                          fused softcap + per-row (max,sumexp,sumlogit)
//  K2  row_reduce        : merge column-block partials per row
//  K3  final_reduce      : scalar loss
//
// Falls back to the R2 reg-staged 128x128 kernel if ws too small.

#define N_ROWS 4096
#define DIM    2048
#define VOCAB  32768
#define IGNORE_IDX (-100)

// fast path geometry
#define BM 256
#define BN 256
#define BK 64
#define NT (DIM / BK)            // 32 K-tiles
#define NCB (VOCAB / BN)         // 128 column blocks
#define ROW_TILES (N_ROWS / BM)  // 16

typedef short s16x8 __attribute__((ext_vector_type(8)));
typedef unsigned short u16x8 __attribute__((ext_vector_type(8)));
typedef float f32x4 __attribute__((ext_vector_type(4)));

#define AS3(p) ((__attribute__((address_space(3))) void*)(p))
#define AS1(p) ((const __attribute__((address_space(1))) void*)(p))

__device__ __forceinline__ float softcap(float x) {
    return 20.0f * tanhf(x * 0.05f);
}

__device__ __forceinline__ unsigned short f2bf(float f) {
    union { float f; unsigned u; } v; v.f = f;
    unsigned r = v.u + 0x7FFFu + ((v.u >> 16) & 1u);
    return (unsigned short)(r >> 16);
}

// ---------------------------------------------------------------------------
// Kc: vectorized f32 -> bf16 conversion (memory-bound)
// ---------------------------------------------------------------------------
__global__ __launch_bounds__(256) void convert_bf16(
    const float* __restrict__ src, unsigned short* __restrict__ dst, int nvec8)
{
    int idx = blockIdx.x * 256 + threadIdx.x;
    int stride = gridDim.x * 256;
    for (int i = idx; i < nvec8; i += stride) {
        const float4* s = (const float4*)(src + (size_t)i * 8);
        float4 a = s[0], b = s[1];
        u16x8 v = { f2bf(a.x), f2bf(a.y), f2bf(a.z), f2bf(a.w),
                    f2bf(b.x), f2bf(b.y), f2bf(b.z), f2bf(b.w) };
        *(u16x8*)(dst + (size_t)i * 8) = v;
    }
}

// ---------------------------------------------------------------------------
// K0: x_t[row] = softcap(dot(hidden[row], weight[tgt])) fp32. 1 wave/row.
// ---------------------------------------------------------------------------
__global__ __launch_bounds__(256) void target_logit(
    const float* __restrict__ hidden, const float* __restrict__ weight,
    const int* __restrict__ targets, float* __restrict__ xtbuf)
{
    int row  = blockIdx.x * 4 + (threadIdx.x >> 6);
    int lane = threadIdx.x & 63;
    if (row >= N_ROWS) return;
    int tgt = targets[row];
    if (tgt < 0 || tgt >= VOCAB) {
        if (lane == 0) xtbuf[row] = 0.f;
        return;
    }
    const float4* h4 = (const float4*)(hidden + (size_t)row * DIM);
    const float4* w4 = (const float4*)(weight + (size_t)tgt * DIM);
    float d = 0.f;
#pragma unroll
    for (int j = 0; j < DIM / 4 / 64; j++) {
        float4 a = h4[lane + 64 * j];
        float4 b = w4[lane + 64 * j];
        d += a.x * b.x + a.y * b.y + a.z * b.z + a.w * b.w;
    }
#pragma unroll
    for (int off = 1; off < 64; off <<= 1) d += __shfl_xor(d, off, 64);
    if (lane == 0) xtbuf[row] = softcap(d);
}

// ---------------------------------------------------------------------------
// K1 fast path: 256x256 8-wave deep-pipelined bf16 GEMM + fused row partials.
//
// LDS (128 KiB): A0 @0, A1 @32K, B0 @64K, B1 @96K. Tile t reads buf t&1,
// stages tile t+1 into buf (t&1)^1. red[2][4][128][3] aliases A1 (safe: last
// tile's wrap-around prefetch targets buf0 only; A1 reads are barrier-done).
//
// Swizzle (T2): logical (row r, col-byte cb in [0,128)) stored at
//   r*128 + (cb ^ ((r&7)<<4)).
// Staging writes linear LDS; the global SOURCE address is inverse-permuted
// (same involution), reads apply the XOR. 16-lane frag reads then span all
// 32 banks at 2-way (free).
//
// Pipeline per K-tile (4 phases, quadrant q = M-frag pair 2q,2q+1):
//   phase q: [ds-read A frags (+ all B frags at q0)]
//            [stage chunk q of tile t+1: q0,q1 = B halves; q2,q3 = A halves]
//            [q1: vmcnt(4) confirms prev tile's q3 A-chunk]
//            [q3: vmcnt(2) confirms this tile's q0-q2 chunks]
//            s_barrier; sched_barrier; setprio(1); 16 MFMA; setprio(0);
//            s_barrier; sched_barrier
// Each wave confirms ITS OWN staged chunks before the barrier that releases
// other waves to read them. vmcnt never drains to 0 in the main loop.
// ---------------------------------------------------------------------------
__device__ __forceinline__ void stage1(
    const unsigned short* gbase, unsigned char* lbase,
    int rows0, int kcol, int laneoff)
{
    __builtin_amdgcn_global_load_lds(
        AS1(gbase + (size_t)rows0 * DIM + kcol + laneoff),
        AS3(lbase + rows0 * 128), 16, 0, 0);
}

__device__ __forceinline__ void stage_phase(
    int q, int kcol, const unsigned short* Asrc, const unsigned short* Bsrc,
    unsigned char* A_st, unsigned char* B_st, int j0, int laneoff)
{
    int j1 = j0 + 1;
    if (q == 0) {
        stage1(Bsrc, B_st, 8 * j0, kcol, laneoff);
        stage1(Bsrc, B_st, 8 * j1, kcol, laneoff);
    } else if (q == 1) {
        stage1(Bsrc, B_st, 128 + 8 * j0, kcol, laneoff);
        stage1(Bsrc, B_st, 128 + 8 * j1, kcol, laneoff);
    } else if (q == 2) {
        stage1(Asrc, A_st, 8 * j0 + (j0 >= 8 ? 64 : 0), kcol, laneoff);
        stage1(Asrc, A_st, 8 * j1 + (j1 >= 8 ? 64 : 0), kcol, laneoff);
    } else {
        stage1(Asrc, A_st, 64 + 8 * j0 + (j0 >= 8 ? 64 : 0), kcol, laneoff);
        stage1(Asrc, A_st, 64 + 8 * j1 + (j1 >= 8 ? 64 : 0), kcol, laneoff);
    }
}

#define LDAF(m, kk) (*(const s16x8*)(A_rd + (wr * 128 + (m) * 16 + li) * 128 \
                                     + ((kk) ? colx1 : colx0)))
#define LDBF(n, kk) (*(const s16x8*)(B_rd + (wc * 64 + (n) * 16 + li) * 128  \
                                     + ((kk) ? colx1 : colx0)))

#define PHASE(q)                                                              \
  {                                                                           \
    s16x8 a0k0 = LDAF(2 * (q), 0),     a0k1 = LDAF(2 * (q), 1);               \
    s16x8 a1k0 = LDAF(2 * (q) + 1, 0), a1k1 = LDAF(2 * (q) + 1, 1);           \
    if ((q) == 0) {                                                           \
      _Pragma("unroll")                                                       \
      for (int n = 0; n < 4; n++) {                                           \
        bfr[n][0] = LDBF(n, 0);                                               \
        bfr[n][1] = LDBF(n, 1);                                               \
      }                                                                       \
    }                                                                         \
    stage_phase((q), kn, Asrc, Bsrc, A_st, B_st, j0, laneoff);                \
    if ((q) == 1) asm volatile("s_waitcnt vmcnt(4)" ::: "memory");            \
    if ((q) == 3) asm volatile("s_waitcnt vmcnt(2)" ::: "memory");            \
    __builtin_amdgcn_s_barrier();                                             \
    __builtin_amdgcn_sched_barrier(0);                                        \
    __builtin_amdgcn_s_setprio(1);                                            \
    _Pragma("unroll")                                                         \
    for (int n = 0; n < 4; n++) {                                             \
      acc[2 * (q)][n]     = __builtin_amdgcn_mfma_f32_16x16x32_bf16(          \
          a0k0, bfr[n][0], acc[2 * (q)][n], 0, 0, 0);                         \
      acc[2 * (q)][n]     = __builtin_amdgcn_mfma_f32_16x16x32_bf16(          \
          a0k1, bfr[n][1], acc[2 * (q)][n], 0, 0, 0);                         \
      acc[2 * (q) + 1][n] = __builtin_amdgcn_mfma_f32_16x16x32_bf16(          \
          a1k0, bfr[n][0], acc[2 * (q) + 1][n], 0, 0, 0);                     \
      acc[2 * (q) + 1][n] = __builtin_amdgcn_mfma_f32_16x16x32_bf16(          \
          a1k1, bfr[n][1], acc[2 * (q) + 1][n], 0, 0, 0);                     \
    }                                                                         \
    __builtin_amdgcn_s_setprio(0);                                            \
    __builtin_amdgcn_s_barrier();                                             \
    __builtin_amdgcn_sched_barrier(0);                                        \
  }

__global__ __launch_bounds__(512, 2) void gemm8ph(
    const unsigned short* __restrict__ A, const unsigned short* __restrict__ B,
    float4* __restrict__ part)
{
    __shared__ unsigned char smem[131072] __attribute__((aligned(16)));

    const int bid  = blockIdx.x;
    const int brow = bid & (ROW_TILES - 1);   // 16 consecutive blocks share B panel
    const int bcol = bid >> 4;
    const int t0   = threadIdx.x;
    const int lane = t0 & 63;
    const int w    = t0 >> 6;                 // 0..7
    const int wr   = w >> 2;                  // 0..1 (M)
    const int wc   = w & 3;                   // 0..3 (N)
    const int li   = lane & 15;
    const int g    = lane >> 4;               // 0..3

    // swizzled column byte offsets for fragment reads (kk = 0,1)
    const int colx0 = (0  + g * 16) ^ ((lane & 7) << 4);
    const int colx1 = (64 + g * 16) ^ ((lane & 7) << 4);

    // staging: lane covers row (lane>>3), 16B slot ((lane&7)^(lane>>3)) — the
    // inverse-swizzled global source for a LINEAR LDS destination.
    const int laneoff = (lane >> 3) * DIM + (((lane & 7) ^ (lane >> 3)) * 8);
    const int j0 = w * 2;

    const unsigned short* Asrc = A + (size_t)brow * BM * DIM;
    const unsigned short* Bsrc = B + (size_t)bcol * BN * DIM;

    f32x4 acc[8][4];
#pragma unroll
    for (int m = 0; m < 8; m++)
#pragma unroll
        for (int n = 0; n < 4; n++) acc[m][n] = (f32x4){0.f, 0.f, 0.f, 0.f};

    // ---- prologue: stage tile 0 into buf0, full drain once ----
    {
        unsigned char* A_st = smem;
        unsigned char* B_st = smem + 65536;
        stage_phase(0, 0, Asrc, Bsrc, A_st, B_st, j0, laneoff);
        stage_phase(1, 0, Asrc, Bsrc, A_st, B_st, j0, laneoff);
        stage_phase(2, 0, Asrc, Bsrc, A_st, B_st, j0, laneoff);
        stage_phase(3, 0, Asrc, Bsrc, A_st, B_st, j0, laneoff);
        asm volatile("s_waitcnt vmcnt(0)" ::: "memory");
        __builtin_amdgcn_s_barrier();
        __builtin_amdgcn_sched_barrier(0);
    }

    s16x8 bfr[4][2];

    for (int t = 0; t < NT; ++t) {
        const int b = t & 1;
        const int kn = ((t + 1) & (NT - 1)) * BK;  // last tile wraps (harmless)
        unsigned char* A_rd = smem + b * 32768;
        unsigned char* B_rd = smem + 65536 + b * 32768;
        unsigned char* A_st = smem + (b ^ 1) * 32768;
        unsigned char* B_st = smem + 65536 + (b ^ 1) * 32768;

        PHASE(0)
        PHASE(1)
        PHASE(2)
        PHASE(3)
    }

    // ---- epilogue: fused per-row reduction over this tile's 256 columns ----
    __syncthreads();   // full drain (also retires wrap-around prefetch)
    float* red = (float*)(smem + 32768);   // [2][4][128][3], aliases A1

#pragma unroll
    for (int m = 0; m < 8; m++) {
#pragma unroll
        for (int r = 0; r < 4; r++) {
            float s0 = softcap(acc[m][0][r]);
            float s1 = softcap(acc[m][1][r]);
            float s2 = softcap(acc[m][2][r]);
            float s3 = softcap(acc[m][3][r]);
            float mx = fmaxf(fmaxf(s0, s1), fmaxf(s2, s3));
#pragma unroll
            for (int off = 1; off < 16; off <<= 1)
                mx = fmaxf(mx, __shfl_xor(mx, off, 64));
            float se = __expf(s0 - mx) + __expf(s1 - mx) +
                       __expf(s2 - mx) + __expf(s3 - mx);
            float st = s0 + s1 + s2 + s3;
#pragma unroll
            for (int off = 1; off < 16; off <<= 1) {
                se += __shfl_xor(se, off, 64);
                st += __shfl_xor(st, off, 64);
            }
            if (li == 0) {
                int rl = m * 16 + g * 4 + r;          // row within wave's 128
                int base = ((wr * 4 + wc) * 128 + rl) * 3;
                red[base + 0] = mx;
                red[base + 1] = se;
                red[base + 2] = st;
            }
        }
    }
    __syncthreads();
    if (t0 < BM) {
        int r   = t0;
        int wr2 = r >> 7;
        int rr  = r & 127;
        int b0  = ((wr2 * 4 + 0) * 128 + rr) * 3;
        float mm = red[b0 + 0], ss = red[b0 + 1], tt = red[b0 + 2];
#pragma unroll
        for (int q = 1; q < 4; q++) {
            int bq = ((wr2 * 4 + q) * 128 + rr) * 3;
            float m2 = red[bq + 0], e2 = red[bq + 1], t2 = red[bq + 2];
            float mn = fmaxf(mm, m2);
            ss = ss * __expf(mm - mn) + e2 * __expf(m2 - mn);
            mm = mn;
            tt += t2;
        }
        part[(size_t)(brow * BM + r) * NCB + bcol] = make_float4(mm, ss, tt, 0.f);
    }
}

// ---------------------------------------------------------------------------
// K1 fallback (R2, verified): reg-staged f32->bf16, 128x128, BK=32.
// ---------------------------------------------------------------------------
__global__ __launch_bounds__(256) void gemm_partial_f32(
    const float* __restrict__ hidden, const float* __restrict__ weight,
    float4* __restrict__ part)
{
    __shared__ unsigned short sA[128 * 32];
    __shared__ unsigned short sB[128 * 32];
    __shared__ float red[4][64][3];

    const int bid  = blockIdx.x;
    const int brow = bid & 31;
    const int bcol = bid >> 5;
    const int t    = threadIdx.x;
    const int lane = t & 63;
    const int w    = t >> 6;
    const int wr   = w >> 1, wc = w & 1;

    const int srow = t >> 1;
    const int scol = (t & 1) * 16;
    const float* gA = hidden + (size_t)(brow * 128 + srow) * DIM + scol;
    const float* gB = weight + (size_t)(bcol * 128 + srow) * DIM + scol;
    unsigned short* wA = &sA[srow * 32 + scol];
    unsigned short* wB = &sB[srow * 32 + scol];

    f32x4 acc[4][4];
#pragma unroll
    for (int m = 0; m < 4; m++)
#pragma unroll
        for (int n = 0; n < 4; n++) acc[m][n] = (f32x4){0.f, 0.f, 0.f, 0.f};

    const unsigned short* pa = &sA[(wr * 64 + (lane & 15)) * 32 + (lane >> 4) * 8];
    const unsigned short* pb = &sB[(wc * 64 + (lane & 15)) * 32 + (lane >> 4) * 8];

    for (int k0 = 0; k0 < DIM; k0 += 32) {
        float4 a0 = *(const float4*)(gA + k0);
        float4 a1 = *(const float4*)(gA + k0 + 4);
        float4 a2 = *(const float4*)(gA + k0 + 8);
        float4 a3 = *(const float4*)(gA + k0 + 12);
        float4 b0 = *(const float4*)(gB + k0);
        float4 b1 = *(const float4*)(gB + k0 + 4);
        float4 b2 = *(const float4*)(gB + k0 + 8);
        float4 b3 = *(const float4*)(gB + k0 + 12);
        __syncthreads();
        u16x8 pa0 = { f2bf(a0.x), f2bf(a0.y), f2bf(a0.z), f2bf(a0.w),
                      f2bf(a1.x), f2bf(a1.y), f2bf(a1.z), f2bf(a1.w) };
        u16x8 pa1 = { f2bf(a2.x), f2bf(a2.y), f2bf(a2.z), f2bf(a2.w),
                      f2bf(a3.x), f2bf(a3.y), f2bf(a3.z), f2bf(a3.w) };
        u16x8 pb0 = { f2bf(b0.x), f2bf(b0.y), f2bf(b0.z), f2bf(b0.w),
                      f2bf(b1.x), f2bf(b1.y), f2bf(b1.z), f2bf(b1.w) };
        u16x8 pb1 = { f2bf(b2.x), f2bf(b2.y), f2bf(b2.z), f2bf(b2.w),
                      f2bf(b3.x), f2bf(b3.y), f2bf(b3.z), f2bf(b3.w) };
        *(u16x8*)wA = pa0;
        *(u16x8*)(wA + 8) = pa1;
        *(u16x8*)wB = pb0;
        *(u16x8*)(wB + 8) = pb1;
        __syncthreads();

        s16x8 afr[4], bfr[4];
#pragma unroll
        for (int m = 0; m < 4; m++) afr[m] = *(const s16x8*)(pa + m * 16 * 32);
#pragma unroll
        for (int n = 0; n < 4; n++) bfr[n] = *(const s16x8*)(pb + n * 16 * 32);
#pragma unroll
        for (int m = 0; m < 4; m++)
#pragma unroll
            for (int n = 0; n < 4; n++)
                acc[m][n] = __builtin_amdgcn_mfma_f32_16x16x32_bf16(
                    afr[m], bfr[n], acc[m][n], 0, 0, 0);
    }

    const int g  = lane >> 4;
    const int li = lane & 15;
#pragma unroll
    for (int m = 0; m < 4; m++) {
#pragma unroll
        for (int r = 0; r < 4; r++) {
            float s0 = softcap(acc[m][0][r]);
            float s1 = softcap(acc[m][1][r]);
            float s2 = softcap(acc[m][2][r]);
            float s3 = softcap(acc[m][3][r]);
            float mx = fmaxf(fmaxf(s0, s1), fmaxf(s2, s3));
#pragma unroll
            for (int off = 1; off < 16; off <<= 1)
                mx = fmaxf(mx, __shfl_xor(mx, off, 64));
            float se = __expf(s0 - mx) + __expf(s1 - mx) +
                       __expf(s2 - mx) + __expf(s3 - mx);
            float st = s0 + s1 + s2 + s3;
#pragma unroll
            for (int off = 1; off < 16; off <<= 1) {
                se += __shfl_xor(se, off, 64);
                st += __shfl_xor(st, off, 64);
            }
            if (li == 0) {
                int rl = m * 16 + g * 4 + r;
                red[w][rl][0] = mx;
                red[w][rl][1] = se;
                red[w][rl][2] = st;
            }
        }
    }
    __syncthreads();
    if (t < 128) {
        int r  = t;
        int wa = (r >> 6) * 2;
        int rr = r & 63;
        float m1 = red[wa][rr][0],     e1 = red[wa][rr][1],     t1 = red[wa][rr][2];
        float m2 = red[wa + 1][rr][0], e2 = red[wa + 1][rr][1], t2 = red[wa + 1][rr][2];
        float mm = fmaxf(m1, m2);
        float ss = e1 * __expf(m1 - mm) + e2 * __expf(m2 - mm);
        float tt = t1 + t2;
        part[(size_t)(brow * 128 + r) * 256 + bcol] = make_float4(mm, ss, tt, 0.f);
    }
}

// ---------------------------------------------------------------------------
// K2: merge ncb column-block partials per row. 1 wave/row.
// ---------------------------------------------------------------------------
__global__ __launch_bounds__(256) void row_reduce(
    const float4* __restrict__ part, const int* __restrict__ targets,
    const float* __restrict__ xtbuf, float* __restrict__ rowbuf, int ncb)
{
    int row  = blockIdx.x * 4 + (threadIdx.x >> 6);
    int lane = threadIdx.x & 63;
    if (row >= N_ROWS) return;
    const float4* p = part + (size_t)row * ncb;
    float4 v = p[lane];
    float m = v.x, s = v.y, st = v.z;
    for (int q = 1; q < ncb / 64; q++) {
        float4 u = p[lane + 64 * q];
        float mm = fmaxf(m, u.x);
        s = s * __expf(m - mm) + u.y * __expf(u.x - mm);
        m = mm;
        st += u.z;
    }
#pragma unroll
    for (int off = 1; off < 64; off <<= 1) {
        float om = __shfl_xor(m, off, 64);
        float os = __shfl_xor(s, off, 64);
        float ot = __shfl_xor(st, off, 64);
        float mm = fmaxf(m, om);
        s = s * __expf(m - mm) + os * __expf(om - mm);
        m = mm;
        st += ot;
    }
    if (lane == 0) {
        float lse = m + logf(s);
        int   tgt = targets[row];
        float vf  = (tgt != IGNORE_IDX) ? 1.f : 0.f;
        float xt  = xtbuf[row];
        float nll = lse - xt;
        float smooth = lse - st * (1.f / (float)VOCAB);
        float rl = 0.9f * nll + 0.1f * smooth;
        rowbuf[row * 3 + 0] = rl * vf;
        rowbuf[row * 3 + 1] = lse * lse * vf;
        rowbuf[row * 3 + 2] = vf;
    }
}

// ---------------------------------------------------------------------------
// K3: deterministic final reduction -> scalar loss.
// ---------------------------------------------------------------------------
__global__ __launch_bounds__(256) void final_reduce(
    const float* __restrict__ rowbuf, float* __restrict__ out)
{
    __shared__ float sl[256], sz[256], sv[256];
    int t = threadIdx.x;
    float ls = 0.f, zs = 0.f, vs = 0.f;
    for (int r = t; r < N_ROWS; r += 256) {
        ls += rowbuf[r * 3 + 0];
        zs += rowbuf[r * 3 + 1];
        vs += rowbuf[r * 3 + 2];
    }
    sl[t] = ls; sz[t] = zs; sv[t] = vs;
    __syncthreads();
    for (int o = 128; o > 0; o >>= 1) {
        if (t < o) { sl[t] += sl[t + o]; sz[t] += sz[t + o]; sv[t] += sv[t + o]; }
        __syncthreads();
    }
    if (t == 0) {
        float nv = fmaxf(sv[0], 1.f);
        out[0] = sl[0] / nv + 1e-4f * (sz[0] / nv);
    }
}

// ---------------------------------------------------------------------------
extern "C" void kernel_launch(void* const* d_in, const int* in_sizes, int n_in,
                              void* d_out, int out_size, void* d_ws, size_t ws_size,
                              hipStream_t stream)
{
    const float* hidden  = (const float*)d_in[0];
    const float* weight  = (const float*)d_in[1];
    const int*   targets = (const int*)d_in[2];
    float*       out     = (float*)d_out;

    char* ws = (char*)d_ws;
    size_t off = 0;
    float4* part = (float4*)(ws + off);
    off += (size_t)N_ROWS * 256 * sizeof(float4);           // 16 MB (max layout)
    float* xtbuf = (float*)(ws + off);
    off += (size_t)N_ROWS * sizeof(float);
    float* rowbuf = (float*)(ws + off);
    off += (size_t)N_ROWS * 3 * sizeof(float);
    off = (off + 255) & ~(size_t)255;
    unsigned short* hidB = (unsigned short*)(ws + off);
    off += (size_t)N_ROWS * DIM * sizeof(unsigned short);   // 16 MB
    unsigned short* wgtB = (unsigned short*)(ws + off);
    off += (size_t)VOCAB * DIM * sizeof(unsigned short);    // 134 MB

    target_logit<<<N_ROWS / 4, 256, 0, stream>>>(hidden, weight, targets, xtbuf);

    if (ws_size >= off) {
        convert_bf16<<<2048, 256, 0, stream>>>(hidden, hidB, N_ROWS * DIM / 8);
        convert_bf16<<<2048, 256, 0, stream>>>(weight, wgtB, VOCAB * DIM / 8);
        gemm8ph<<<ROW_TILES * (VOCAB / BN), 512, 0, stream>>>(hidB, wgtB, part);
        row_reduce<<<N_ROWS / 4, 256, 0, stream>>>(part, targets, xtbuf, rowbuf, NCB);
    } else {
        gemm_partial_f32<<<32 * 256, 256, 0, stream>>>(hidden, weight, part);
        row_reduce<<<N_ROWS / 4, 256, 0, stream>>>(part, targets, xtbuf, rowbuf, 256);
    }

    final_reduce<<<1, 256, 0, stream>>>(rowbuf, out);
}

// Round 4
// 650.675 us; speedup vs baseline: 1.7815x; 1.0041x over previous
//
#include <hip/hip_runtime.h>
#include <hip/hip_bf16.h>
#include <math.h>

// ChunkedLinearCrossEntropyLoss fused kernel for MI355X (gfx950) — R4
//
// hidden[4096,2048] f32, weight[32768,2048] f32, targets[4096] i32 -> scalar
//
//  Kc  convert_bf16 : f32 -> bf16 copies of hidden and weight in ws
//  K0  target_logit : x_t[row] = softcap(h[row].w[tgt[row]]) fp32
//  K1  gemm8ph      : 256x256 tile, BK=64, 8 waves, DEEP pipeline:
//                     chunk for tile T issued at T-2/T-1 (5-7 phase lag),
//                     staging into the buffer being read (WAR-safe via phase
//                     retirement), vmcnt(8) waits only. T2 swizzle + setprio.
//  K2  row_reduce   : merge column-block partials per row
//  K3  final_reduce : scalar loss

#define N_ROWS 4096
#define DIM    2048
#define VOCAB  32768
#define IGNORE_IDX (-100)

#define BM 256
#define BN 256
#define BK 64
#define NT (DIM / BK)            // 32 K-tiles
#define NCB (VOCAB / BN)         // 128 column blocks
#define ROW_TILES (N_ROWS / BM)  // 16

typedef short s16x8 __attribute__((ext_vector_type(8)));
typedef unsigned short u16x8 __attribute__((ext_vector_type(8)));
typedef float f32x4 __attribute__((ext_vector_type(4)));

#define AS3(p) ((__attribute__((address_space(3))) void*)(p))
#define AS1(p) ((const __attribute__((address_space(1))) void*)(p))

__device__ __forceinline__ float softcap(float x) {
    return 20.0f * tanhf(x * 0.05f);
}

__device__ __forceinline__ unsigned short f2bf(float f) {
    union { float f; unsigned u; } v; v.f = f;
    unsigned r = v.u + 0x7FFFu + ((v.u >> 16) & 1u);
    return (unsigned short)(r >> 16);
}

// ---------------------------------------------------------------------------
// Kc: vectorized f32 -> bf16 conversion (memory-bound)
// ---------------------------------------------------------------------------
__global__ __launch_bounds__(256) void convert_bf16(
    const float* __restrict__ src, unsigned short* __restrict__ dst, int nvec8)
{
    int idx = blockIdx.x * 256 + threadIdx.x;
    int stride = gridDim.x * 256;
    for (int i = idx; i < nvec8; i += stride) {
        const float4* s = (const float4*)(src + (size_t)i * 8);
        float4 a = s[0], b = s[1];
        u16x8 v = { f2bf(a.x), f2bf(a.y), f2bf(a.z), f2bf(a.w),
                    f2bf(b.x), f2bf(b.y), f2bf(b.z), f2bf(b.w) };
        *(u16x8*)(dst + (size_t)i * 8) = v;
    }
}

// ---------------------------------------------------------------------------
// K0: x_t[row] = softcap(dot(hidden[row], weight[tgt])) fp32. 1 wave/row.
// ---------------------------------------------------------------------------
__global__ __launch_bounds__(256) void target_logit(
    const float* __restrict__ hidden, const float* __restrict__ weight,
    const int* __restrict__ targets, float* __restrict__ xtbuf)
{
    int row  = blockIdx.x * 4 + (threadIdx.x >> 6);
    int lane = threadIdx.x & 63;
    if (row >= N_ROWS) return;
    int tgt = targets[row];
    if (tgt < 0 || tgt >= VOCAB) {
        if (lane == 0) xtbuf[row] = 0.f;
        return;
    }
    const float4* h4 = (const float4*)(hidden + (size_t)row * DIM);
    const float4* w4 = (const float4*)(weight + (size_t)tgt * DIM);
    float d = 0.f;
#pragma unroll
    for (int j = 0; j < DIM / 4 / 64; j++) {
        float4 a = h4[lane + 64 * j];
        float4 b = w4[lane + 64 * j];
        d += a.x * b.x + a.y * b.y + a.z * b.z + a.w * b.w;
    }
#pragma unroll
    for (int off = 1; off < 64; off <<= 1) d += __shfl_xor(d, off, 64);
    if (lane == 0) xtbuf[row] = softcap(d);
}

// ---------------------------------------------------------------------------
// K1: 256x256 8-wave deep-pipelined bf16 GEMM + fused row partials.
//
// LDS: A0 @0, A1 @32K, B0 @64K, B1 @96K, dummy @128K (1KB).
// Tile t reads buf t&1.
//
// Chunks (16 KB each, 2 global_load_lds per wave):
//   B0 = B rows [0,128), B1 = B rows [128,256)
//   A0 = A rows [0,64)u[128,192), A1 = A rows [64,128)u[192,256)
// Read schedule within tile t: phase q reads A rows [32q,32q+32) (+128 for
// wr=1) — A0 at phases 0,1; A1 at phases 2,3; ALL of B at phase 0.
//
// Staging (issue) schedule for a consume-tile T (lag 5-7 phases):
//   (T,B0)@T-2 p1, (T,B1)@T-2 p2, (T,A0)@T-2 p3  -> into buf being read
//      (region's last read retired >=1 phase earlier, barriers order it)
//   (T,A1)@T-1 p0                                -> other buffer
// Waits, both vmcnt(8) (allow newest 4 chunks in flight):
//   W1 at t p1 end: confirms (t,A1)  (needed t p2)
//   W2 at t p3 end: confirms (t+1,{B0,B1,A0}) (needed t+1 p0)
// Chunks with consume-tile >= NT land in the dummy region (counts stay exact).
// ---------------------------------------------------------------------------
__device__ __forceinline__ void stage_chunk(
    int kind, int ct, const unsigned short* Asrc, const unsigned short* Bsrc,
    unsigned char* smem, int j0, int laneoff)
{
    // kind: 0=B0, 1=B1, 2=A0, 3=A1
    const int kcol = (ct & (NT - 1)) * BK;
    const int b = ct & 1;
    const int dum = (ct >= NT);
    const unsigned short* src;
    int base, r0, r1;
    if (kind <= 1) {
        src = Bsrc; base = 65536 + b * 32768;
        r0 = kind * 128 + 8 * j0;
        r1 = r0 + 8;
    } else {
        src = Asrc; base = b * 32768;
        int add = (kind == 2) ? 0 : 64;
        r0 = add + 8 * j0       + ((j0     >= 8) ? 64 : 0);
        r1 = add + 8 * (j0 + 1) + ((j0 + 1 >= 8) ? 64 : 0);
    }
    int l0 = dum ? 131072 : base + r0 * 128;
    int l1 = dum ? 131072 : base + r1 * 128;
    __builtin_amdgcn_global_load_lds(
        AS1(src + (size_t)r0 * DIM + kcol + laneoff), AS3(smem + l0), 16, 0, 0);
    __builtin_amdgcn_global_load_lds(
        AS1(src + (size_t)r1 * DIM + kcol + laneoff), AS3(smem + l1), 16, 0, 0);
}

#define LDAF(m, kk) (*(const s16x8*)(A_rd + (wr * 128 + (m) * 16 + li) * 128 \
                                     + ((kk) ? colx1 : colx0)))
#define LDBF(n, kk) (*(const s16x8*)(B_rd + (wc * 64 + (n) * 16 + li) * 128  \
                                     + ((kk) ? colx1 : colx0)))

#define PHASE(q, KIND, CT, WAITP)                                             \
  {                                                                           \
    s16x8 a0k0 = LDAF(2 * (q), 0),     a0k1 = LDAF(2 * (q), 1);               \
    s16x8 a1k0 = LDAF(2 * (q) + 1, 0), a1k1 = LDAF(2 * (q) + 1, 1);           \
    if ((q) == 0) {                                                           \
      _Pragma("unroll")                                                       \
      for (int n = 0; n < 4; n++) {                                           \
        bfr[n][0] = LDBF(n, 0);                                               \
        bfr[n][1] = LDBF(n, 1);                                               \
      }                                                                       \
    }                                                                         \
    stage_chunk((KIND), (CT), Asrc, Bsrc, smem, j0, laneoff);                 \
    __builtin_amdgcn_s_barrier();                                             \
    __builtin_amdgcn_sched_barrier(0);                                        \
    __builtin_amdgcn_s_setprio(1);                                            \
    _Pragma("unroll")                                                         \
    for (int n = 0; n < 4; n++) {                                             \
      acc[2 * (q)][n]     = __builtin_amdgcn_mfma_f32_16x16x32_bf16(          \
          a0k0, bfr[n][0], acc[2 * (q)][n], 0, 0, 0);                         \
      acc[2 * (q)][n]     = __builtin_amdgcn_mfma_f32_16x16x32_bf16(          \
          a0k1, bfr[n][1], acc[2 * (q)][n], 0, 0, 0);                         \
      acc[2 * (q) + 1][n] = __builtin_amdgcn_mfma_f32_16x16x32_bf16(          \
          a1k0, bfr[n][0], acc[2 * (q) + 1][n], 0, 0, 0);                     \
      acc[2 * (q) + 1][n] = __builtin_amdgcn_mfma_f32_16x16x32_bf16(          \
          a1k1, bfr[n][1], acc[2 * (q) + 1][n], 0, 0, 0);                     \
    }                                                                         \
    __builtin_amdgcn_s_setprio(0);                                            \
    if (WAITP) asm volatile("s_waitcnt vmcnt(8)" ::: "memory");               \
    __builtin_amdgcn_s_barrier();                                             \
    __builtin_amdgcn_sched_barrier(0);                                        \
  }

__global__ __launch_bounds__(512, 2) void gemm8ph(
    const unsigned short* __restrict__ A, const unsigned short* __restrict__ B,
    float4* __restrict__ part)
{
    __shared__ unsigned char smem[131072 + 1024] __attribute__((aligned(16)));

    const int bid  = blockIdx.x;
    const int brow = bid & (ROW_TILES - 1);   // 16 consecutive blocks share B panel
    const int bcol = bid >> 4;
    const int t0   = threadIdx.x;
    const int lane = t0 & 63;
    const int w    = t0 >> 6;                 // 0..7
    const int wr   = w >> 2;                  // 0..1 (M)
    const int wc   = w & 3;                   // 0..3 (N)
    const int li   = lane & 15;
    const int g    = lane >> 4;               // 0..3

    // swizzled column byte offsets for fragment reads (kk = 0,1)
    const int colx0 = (0  + g * 16) ^ ((lane & 7) << 4);
    const int colx1 = (64 + g * 16) ^ ((lane & 7) << 4);

    // staging: lane covers row (lane>>3), 16B slot ((lane&7)^(lane>>3)) — the
    // inverse-swizzled global source for a LINEAR LDS destination.
    const int laneoff = (lane >> 3) * DIM + (((lane & 7) ^ (lane >> 3)) * 8);
    const int j0 = w * 2;

    const unsigned short* Asrc = A + (size_t)brow * BM * DIM;
    const unsigned short* Bsrc = B + (size_t)bcol * BN * DIM;

    f32x4 acc[8][4];
#pragma unroll
    for (int m = 0; m < 8; m++)
#pragma unroll
        for (int n = 0; n < 4; n++) acc[m][n] = (f32x4){0.f, 0.f, 0.f, 0.f};

    // ---- prologue: (0,B0)(0,B1)(0,A0)(0,A1)(1,B0)(1,B1)(1,A0); vmcnt(8)
    // confirms exactly (0,B0),(0,B1),(0,A0) — what tile 0 phase 0 needs.
    stage_chunk(0, 0, Asrc, Bsrc, smem, j0, laneoff);
    stage_chunk(1, 0, Asrc, Bsrc, smem, j0, laneoff);
    stage_chunk(2, 0, Asrc, Bsrc, smem, j0, laneoff);
    stage_chunk(3, 0, Asrc, Bsrc, smem, j0, laneoff);
    stage_chunk(0, 1, Asrc, Bsrc, smem, j0, laneoff);
    stage_chunk(1, 1, Asrc, Bsrc, smem, j0, laneoff);
    stage_chunk(2, 1, Asrc, Bsrc, smem, j0, laneoff);
    asm volatile("s_waitcnt vmcnt(8)" ::: "memory");
    __builtin_amdgcn_s_barrier();
    __builtin_amdgcn_sched_barrier(0);

    s16x8 bfr[4][2];

    for (int t = 0; t < NT; ++t) {
        const int b = t & 1;
        unsigned char* A_rd = smem + b * 32768;
        unsigned char* B_rd = smem + 65536 + b * 32768;

        PHASE(0, 3, t + 1, 0)   // stage (t+1, A1) -> other buffer
        PHASE(1, 0, t + 2, 1)   // stage (t+2, B0) -> this buffer; W1
        PHASE(2, 1, t + 2, 0)   // stage (t+2, B1)
        PHASE(3, 2, t + 2, 1)   // stage (t+2, A0); W2
    }

    // ---- epilogue: fused per-row reduction over this tile's 256 columns ----
    __syncthreads();   // full drain (also retires dummy wrap prefetches)
    float* red = (float*)(smem + 32768);   // [8][128][3], aliases A buf1

#pragma unroll
    for (int m = 0; m < 8; m++) {
#pragma unroll
        for (int r = 0; r < 4; r++) {
            float s0 = softcap(acc[m][0][r]);
            float s1 = softcap(acc[m][1][r]);
            float s2 = softcap(acc[m][2][r]);
            float s3 = softcap(acc[m][3][r]);
            float mx = fmaxf(fmaxf(s0, s1), fmaxf(s2, s3));
#pragma unroll
            for (int off = 1; off < 16; off <<= 1)
                mx = fmaxf(mx, __shfl_xor(mx, off, 64));
            float se = __expf(s0 - mx) + __expf(s1 - mx) +
                       __expf(s2 - mx) + __expf(s3 - mx);
            float st = s0 + s1 + s2 + s3;
#pragma unroll
            for (int off = 1; off < 16; off <<= 1) {
                se += __shfl_xor(se, off, 64);
                st += __shfl_xor(st, off, 64);
            }
            if (li == 0) {
                int rl = m * 16 + g * 4 + r;          // row within wave's 128
                int base = ((wr * 4 + wc) * 128 + rl) * 3;
                red[base + 0] = mx;
                red[base + 1] = se;
                red[base + 2] = st;
            }
        }
    }
    __syncthreads();
    if (t0 < BM) {
        int r   = t0;
        int wr2 = r >> 7;
        int rr  = r & 127;
        int b0  = ((wr2 * 4 + 0) * 128 + rr) * 3;
        float mm = red[b0 + 0], ss = red[b0 + 1], tt = red[b0 + 2];
#pragma unroll
        for (int q = 1; q < 4; q++) {
            int bq = ((wr2 * 4 + q) * 128 + rr) * 3;
            float m2 = red[bq + 0], e2 = red[bq + 1], t2 = red[bq + 2];
            float mn = fmaxf(mm, m2);
            ss = ss * __expf(mm - mn) + e2 * __expf(m2 - mn);
            mm = mn;
            tt += t2;
        }
        part[(size_t)(brow * BM + r) * NCB + bcol] = make_float4(mm, ss, tt, 0.f);
    }
}

// ---------------------------------------------------------------------------
// K1 fallback (R2, verified): reg-staged f32->bf16, 128x128, BK=32.
// ---------------------------------------------------------------------------
__global__ __launch_bounds__(256) void gemm_partial_f32(
    const float* __restrict__ hidden, const float* __restrict__ weight,
    float4* __restrict__ part)
{
    __shared__ unsigned short sA[128 * 32];
    __shared__ unsigned short sB[128 * 32];
    __shared__ float red[4][64][3];

    const int bid  = blockIdx.x;
    const int brow = bid & 31;
    const int bcol = bid >> 5;
    const int t    = threadIdx.x;
    const int lane = t & 63;
    const int w    = t >> 6;
    const int wr   = w >> 1, wc = w & 1;

    const int srow = t >> 1;
    const int scol = (t & 1) * 16;
    const float* gA = hidden + (size_t)(brow * 128 + srow) * DIM + scol;
    const float* gB = weight + (size_t)(bcol * 128 + srow) * DIM + scol;
    unsigned short* wA = &sA[srow * 32 + scol];
    unsigned short* wB = &sB[srow * 32 + scol];

    f32x4 acc[4][4];
#pragma unroll
    for (int m = 0; m < 4; m++)
#pragma unroll
        for (int n = 0; n < 4; n++) acc[m][n] = (f32x4){0.f, 0.f, 0.f, 0.f};

    const unsigned short* pa = &sA[(wr * 64 + (lane & 15)) * 32 + (lane >> 4) * 8];
    const unsigned short* pb = &sB[(wc * 64 + (lane & 15)) * 32 + (lane >> 4) * 8];

    for (int k0 = 0; k0 < DIM; k0 += 32) {
        float4 a0 = *(const float4*)(gA + k0);
        float4 a1 = *(const float4*)(gA + k0 + 4);
        float4 a2 = *(const float4*)(gA + k0 + 8);
        float4 a3 = *(const float4*)(gA + k0 + 12);
        float4 b0 = *(const float4*)(gB + k0);
        float4 b1 = *(const float4*)(gB + k0 + 4);
        float4 b2 = *(const float4*)(gB + k0 + 8);
        float4 b3 = *(const float4*)(gB + k0 + 12);
        __syncthreads();
        u16x8 pa0 = { f2bf(a0.x), f2bf(a0.y), f2bf(a0.z), f2bf(a0.w),
                      f2bf(a1.x), f2bf(a1.y), f2bf(a1.z), f2bf(a1.w) };
        u16x8 pa1 = { f2bf(a2.x), f2bf(a2.y), f2bf(a2.z), f2bf(a2.w),
                      f2bf(a3.x), f2bf(a3.y), f2bf(a3.z), f2bf(a3.w) };
        u16x8 pb0 = { f2bf(b0.x), f2bf(b0.y), f2bf(b0.z), f2bf(b0.w),
                      f2bf(b1.x), f2bf(b1.y), f2bf(b1.z), f2bf(b1.w) };
        u16x8 pb1 = { f2bf(b2.x), f2bf(b2.y), f2bf(b2.z), f2bf(b2.w),
                      f2bf(b3.x), f2bf(b3.y), f2bf(b3.z), f2bf(b3.w) };
        *(u16x8*)wA = pa0;
        *(u16x8*)(wA + 8) = pa1;
        *(u16x8*)wB = pb0;
        *(u16x8*)(wB + 8) = pb1;
        __syncthreads();

        s16x8 afr[4], bfr[4];
#pragma unroll
        for (int m = 0; m < 4; m++) afr[m] = *(const s16x8*)(pa + m * 16 * 32);
#pragma unroll
        for (int n = 0; n < 4; n++) bfr[n] = *(const s16x8*)(pb + n * 16 * 32);
#pragma unroll
        for (int m = 0; m < 4; m++)
#pragma unroll
            for (int n = 0; n < 4; n++)
                acc[m][n] = __builtin_amdgcn_mfma_f32_16x16x32_bf16(
                    afr[m], bfr[n], acc[m][n], 0, 0, 0);
    }

    const int g  = lane >> 4;
    const int li = lane & 15;
#pragma unroll
    for (int m = 0; m < 4; m++) {
#pragma unroll
        for (int r = 0; r < 4; r++) {
            float s0 = softcap(acc[m][0][r]);
            float s1 = softcap(acc[m][1][r]);
            float s2 = softcap(acc[m][2][r]);
            float s3 = softcap(acc[m][3][r]);
            float mx = fmaxf(fmaxf(s0, s1), fmaxf(s2, s3));
#pragma unroll
            for (int off = 1; off < 16; off <<= 1)
                mx = fmaxf(mx, __shfl_xor(mx, off, 64));
            float se = __expf(s0 - mx) + __expf(s1 - mx) +
                       __expf(s2 - mx) + __expf(s3 - mx);
            float st = s0 + s1 + s2 + s3;
#pragma unroll
            for (int off = 1; off < 16; off <<= 1) {
                se += __shfl_xor(se, off, 64);
                st += __shfl_xor(st, off, 64);
            }
            if (li == 0) {
                int rl = m * 16 + g * 4 + r;
                red[w][rl][0] = mx;
                red[w][rl][1] = se;
                red[w][rl][2] = st;
            }
        }
    }
    __syncthreads();
    if (t < 128) {
        int r  = t;
        int wa = (r >> 6) * 2;
        int rr = r & 63;
        float m1 = red[wa][rr][0],     e1 = red[wa][rr][1],     t1 = red[wa][rr][2];
        float m2 = red[wa + 1][rr][0], e2 = red[wa + 1][rr][1], t2 = red[wa + 1][rr][2];
        float mm = fmaxf(m1, m2);
        float ss = e1 * __expf(m1 - mm) + e2 * __expf(m2 - mm);
        float tt = t1 + t2;
        part[(size_t)(brow * 128 + r) * 256 + bcol] = make_float4(mm, ss, tt, 0.f);
    }
}

// ---------------------------------------------------------------------------
// K2: merge ncb column-block partials per row. 1 wave/row.
// ---------------------------------------------------------------------------
__global__ __launch_bounds__(256) void row_reduce(
    const float4* __restrict__ part, const int* __restrict__ targets,
    const float* __restrict__ xtbuf, float* __restrict__ rowbuf, int ncb)
{
    int row  = blockIdx.x * 4 + (threadIdx.x >> 6);
    int lane = threadIdx.x & 63;
    if (row >= N_ROWS) return;
    const float4* p = part + (size_t)row * ncb;
    float4 v = p[lane];
    float m = v.x, s = v.y, st = v.z;
    for (int q = 1; q < ncb / 64; q++) {
        float4 u = p[lane + 64 * q];
        float mm = fmaxf(m, u.x);
        s = s * __expf(m - mm) + u.y * __expf(u.x - mm);
        m = mm;
        st += u.z;
    }
#pragma unroll
    for (int off = 1; off < 64; off <<= 1) {
        float om = __shfl_xor(m, off, 64);
        float os = __shfl_xor(s, off, 64);
        float ot = __shfl_xor(st, off, 64);
        float mm = fmaxf(m, om);
        s = s * __expf(m - mm) + os * __expf(om - mm);
        m = mm;
        st += ot;
    }
    if (lane == 0) {
        float lse = m + logf(s);
        int   tgt = targets[row];
        float vf  = (tgt != IGNORE_IDX) ? 1.f : 0.f;
        float xt  = xtbuf[row];
        float nll = lse - xt;
        float smooth = lse - st * (1.f / (float)VOCAB);
        float rl = 0.9f * nll + 0.1f * smooth;
        rowbuf[row * 3 + 0] = rl * vf;
        rowbuf[row * 3 + 1] = lse * lse * vf;
        rowbuf[row * 3 + 2] = vf;
    }
}

// ---------------------------------------------------------------------------
// K3: deterministic final reduction -> scalar loss.
// ---------------------------------------------------------------------------
__global__ __launch_bounds__(256) void final_reduce(
    const float* __restrict__ rowbuf, float* __restrict__ out)
{
    __shared__ float sl[256], sz[256], sv[256];
    int t = threadIdx.x;
    float ls = 0.f, zs = 0.f, vs = 0.f;
    for (int r = t; r < N_ROWS; r += 256) {
        ls += rowbuf[r * 3 + 0];
        zs += rowbuf[r * 3 + 1];
        vs += rowbuf[r * 3 + 2];
    }
    sl[t] = ls; sz[t] = zs; sv[t] = vs;
    __syncthreads();
    for (int o = 128; o > 0; o >>= 1) {
        if (t < o) { sl[t] += sl[t + o]; sz[t] += sz[t + o]; sv[t] += sv[t + o]; }
        __syncthreads();
    }
    if (t == 0) {
        float nv = fmaxf(sv[0], 1.f);
        out[0] = sl[0] / nv + 1e-4f * (sz[0] / nv);
    }
}

// ---------------------------------------------------------------------------
extern "C" void kernel_launch(void* const* d_in, const int* in_sizes, int n_in,
                              void* d_out, int out_size, void* d_ws, size_t ws_size,
                              hipStream_t stream)
{
    const float* hidden  = (const float*)d_in[0];
    const float* weight  = (const float*)d_in[1];
    const int*   targets = (const int*)d_in[2];
    float*       out     = (float*)d_out;

    char* ws = (char*)d_ws;
    size_t off = 0;
    float4* part = (float4*)(ws + off);
    off += (size_t)N_ROWS * 256 * sizeof(float4);           // 16 MB (max layout)
    float* xtbuf = (float*)(ws + off);
    off += (size_t)N_ROWS * sizeof(float);
    float* rowbuf = (float*)(ws + off);
    off += (size_t)N_ROWS * 3 * sizeof(float);
    off = (off + 255) & ~(size_t)255;
    unsigned short* hidB = (unsigned short*)(ws + off);
    off += (size_t)N_ROWS * DIM * sizeof(unsigned short);   // 16 MB
    unsigned short* wgtB = (unsigned short*)(ws + off);
    off += (size_t)VOCAB * DIM * sizeof(unsigned short);    // 134 MB

    target_logit<<<N_ROWS / 4, 256, 0, stream>>>(hidden, weight, targets, xtbuf);

    if (ws_size >= off) {
        convert_bf16<<<2048, 256, 0, stream>>>(hidden, hidB, N_ROWS * DIM / 8);
        convert_bf16<<<2048, 256, 0, stream>>>(weight, wgtB, VOCAB * DIM / 8);
        gemm8ph<<<ROW_TILES * (VOCAB / BN), 512, 0, stream>>>(hidB, wgtB, part);
        row_reduce<<<N_ROWS / 4, 256, 0, stream>>>(part, targets, xtbuf, rowbuf, NCB);
    } else {
        gemm_partial_f32<<<32 * 256, 256, 0, stream>>>(hidden, weight, part);
        row_reduce<<<N_ROWS / 4, 256, 0, stream>>>(part, targets, xtbuf, rowbuf, 256);
    }

    final_reduce<<<1, 256, 0, stream>>>(rowbuf, out);
}

// Round 5
// 588.898 us; speedup vs baseline: 1.9684x; 1.1049x over previous
//
#include <hip/hip_runtime.h>
#include <hip/hip_bf16.h>
#include <math.h>

// ChunkedLinearCrossEntropyLoss fused kernel for MI355X (gfx950) — R5
//
// hidden[4096,2048] f32, weight[32768,2048] f32, targets[4096] i32 -> scalar
//
//  Kc  convert_bf16 : f32 -> bf16 copies of hidden and weight in ws
//  K0  target_logit : x_t[row] = softcap(h[row].w[tgt[row]]) fp32
//  K1  gemm8ph      : 256x256 tile, BK=64, 8 waves. 2 windows/tile, ONE
//                     barrier per window (no mid-window barrier -> LDS reads
//                     overlap MFMA across waves). Deep staging: chunk for
//                     tile T issued 2 windows before its vmcnt(8) confirm.
//                     T2 swizzle (0 bank conflicts) + setprio.
//                     Softcap bounds logits to +-20 -> NO online max needed;
//                     partials are plain (sum_exp, sum_logit).
//  K2  row_reduce   : sum column-block partials per row -> row loss terms
//  K3  final_reduce : scalar loss

#define N_ROWS 4096
#define DIM    2048
#define VOCAB  32768
#define IGNORE_IDX (-100)

#define BM 256
#define BN 256
#define BK 64
#define NT (DIM / BK)            // 32 K-tiles
#define NCB (VOCAB / BN)         // 128 column blocks
#define ROW_TILES (N_ROWS / BM)  // 16

typedef short s16x8 __attribute__((ext_vector_type(8)));
typedef unsigned short u16x8 __attribute__((ext_vector_type(8)));
typedef float f32x4 __attribute__((ext_vector_type(4)));

#define AS3(p) ((__attribute__((address_space(3))) void*)(p))
#define AS1(p) ((const __attribute__((address_space(1))) void*)(p))

// 20*tanh(x/20) via hardware exp; clamp keeps exp finite for any input.
__device__ __forceinline__ float softcap(float x) {
    x = fminf(80.f, fmaxf(-80.f, x));
    float e = __expf(x * 0.1f);                    // e^(2*(x/20))
    return 20.f * (e - 1.f) * __builtin_amdgcn_rcpf(e + 1.f);
}

// f32 -> bf16 round-to-nearest-even
__device__ __forceinline__ unsigned short f2bf(float f) {
    union { float f; unsigned u; } v; v.f = f;
    unsigned r = v.u + 0x7FFFu + ((v.u >> 16) & 1u);
    return (unsigned short)(r >> 16);
}

// ---------------------------------------------------------------------------
// Kc: vectorized f32 -> bf16 conversion (memory-bound)
// ---------------------------------------------------------------------------
__global__ __launch_bounds__(256) void convert_bf16(
    const float* __restrict__ src, unsigned short* __restrict__ dst, int nvec8)
{
    int idx = blockIdx.x * 256 + threadIdx.x;
    int stride = gridDim.x * 256;
    for (int i = idx; i < nvec8; i += stride) {
        const float4* s = (const float4*)(src + (size_t)i * 8);
        float4 a = s[0], b = s[1];
        u16x8 v = { f2bf(a.x), f2bf(a.y), f2bf(a.z), f2bf(a.w),
                    f2bf(b.x), f2bf(b.y), f2bf(b.z), f2bf(b.w) };
        *(u16x8*)(dst + (size_t)i * 8) = v;
    }
}

// ---------------------------------------------------------------------------
// K0: x_t[row] = softcap(dot(hidden[row], weight[tgt])) fp32. 1 wave/row.
// ---------------------------------------------------------------------------
__global__ __launch_bounds__(256) void target_logit(
    const float* __restrict__ hidden, const float* __restrict__ weight,
    const int* __restrict__ targets, float* __restrict__ xtbuf)
{
    int row  = blockIdx.x * 4 + (threadIdx.x >> 6);
    int lane = threadIdx.x & 63;
    if (row >= N_ROWS) return;
    int tgt = targets[row];
    if (tgt < 0 || tgt >= VOCAB) {
        if (lane == 0) xtbuf[row] = 0.f;
        return;
    }
    const float4* h4 = (const float4*)(hidden + (size_t)row * DIM);
    const float4* w4 = (const float4*)(weight + (size_t)tgt * DIM);
    float d = 0.f;
#pragma unroll
    for (int j = 0; j < DIM / 4 / 64; j++) {
        float4 a = h4[lane + 64 * j];
        float4 b = w4[lane + 64 * j];
        d += a.x * b.x + a.y * b.y + a.z * b.z + a.w * b.w;
    }
#pragma unroll
    for (int off = 1; off < 64; off <<= 1) d += __shfl_xor(d, off, 64);
    if (lane == 0) xtbuf[row] = softcap(d);
}

// ---------------------------------------------------------------------------
// K1: 256x256 8-wave bf16 GEMM, 2 windows/tile, fused row partials.
//
// LDS: A0buf @0, A1buf @32K, B0buf @64K, B1buf @96K, dummy @128K (1KB).
// Tile t reads buf t&1.
// Chunks (16 KB, 2 global_load_lds/wave): B0=B rows[0,128); B1=B rows[128,256);
// A0=A rows[0,64)u[128,192); A1=A rows[64,128)u[192,256).
//
// tile t, window 0 (computes acc[0..3] = A rows wr*128+[0,64)):
//   ds_read 8 B-frags + 4 A0-frag pairs; stage (t+1,A1) -> other buffer;
//   32 MFMA; vmcnt(8); s_barrier.
// tile t, window 1 (computes acc[4..7] = A rows wr*128+[64,128)):
//   ds_read 4 A1-frag pairs; stage (t+2,B0),(t+2,B1),(t+2,A0) -> buffer
//   being read (regions' reads all retired in window 0);
//   32 MFMA; vmcnt(8); s_barrier.
// FIFO: after each wait exactly 8 loads outstanding; every confirmed chunk
// was issued >=2 windows (~2500 cyc) earlier. Chunks with ct>=NT land in the
// dummy region (keeps vmcnt counts exact).
// ---------------------------------------------------------------------------
__device__ __forceinline__ void stage_chunk(
    int kind, int ct, const unsigned short* Asrc, const unsigned short* Bsrc,
    unsigned char* smem, int j0, int laneoff)
{
    // kind: 0=B0, 1=B1, 2=A0, 3=A1
    const int kcol = (ct & (NT - 1)) * BK;
    const int b = ct & 1;
    const int dum = (ct >= NT);
    const unsigned short* src;
    int base, r0, r1;
    if (kind <= 1) {
        src = Bsrc; base = 65536 + b * 32768;
        r0 = kind * 128 + 8 * j0;
        r1 = r0 + 8;
    } else {
        src = Asrc; base = b * 32768;
        int add = (kind == 2) ? 0 : 64;
        r0 = add + 8 * j0       + ((j0     >= 8) ? 64 : 0);
        r1 = add + 8 * (j0 + 1) + ((j0 + 1 >= 8) ? 64 : 0);
    }
    int l0 = dum ? 131072 : base + r0 * 128;
    int l1 = dum ? 131072 : base + r1 * 128;
    __builtin_amdgcn_global_load_lds(
        AS1(src + (size_t)r0 * DIM + kcol + laneoff), AS3(smem + l0), 16, 0, 0);
    __builtin_amdgcn_global_load_lds(
        AS1(src + (size_t)r1 * DIM + kcol + laneoff), AS3(smem + l1), 16, 0, 0);
}

#define LDAF(m, kk) (*(const s16x8*)(A_rd + (wr * 128 + (m) * 16 + li) * 128 \
                                     + ((kk) ? colx1 : colx0)))
#define LDBF(n, kk) (*(const s16x8*)(B_rd + (wc * 64 + (n) * 16 + li) * 128  \
                                     + ((kk) ? colx1 : colx0)))

__global__ __launch_bounds__(512, 2) void gemm8ph(
    const unsigned short* __restrict__ A, const unsigned short* __restrict__ B,
    float2* __restrict__ part)
{
    __shared__ unsigned char smem[131072 + 1024] __attribute__((aligned(16)));

    const int bid  = blockIdx.x;
    const int brow = bid & (ROW_TILES - 1);   // 16 consecutive blocks share B panel
    const int bcol = bid >> 4;
    const int t0   = threadIdx.x;
    const int lane = t0 & 63;
    const int w    = t0 >> 6;                 // 0..7
    const int wr   = w >> 2;                  // 0..1 (M)
    const int wc   = w & 3;                   // 0..3 (N)
    const int li   = lane & 15;
    const int g    = lane >> 4;               // 0..3

    // swizzled column byte offsets for fragment reads (kk = 0,1)
    const int colx0 = (0  + g * 16) ^ ((lane & 7) << 4);
    const int colx1 = (64 + g * 16) ^ ((lane & 7) << 4);

    // staging: lane covers row (lane>>3), 16B slot ((lane&7)^(lane>>3)) — the
    // inverse-swizzled global source for a LINEAR LDS destination.
    const int laneoff = (lane >> 3) * DIM + (((lane & 7) ^ (lane >> 3)) * 8);
    const int j0 = w * 2;

    const unsigned short* Asrc = A + (size_t)brow * BM * DIM;
    const unsigned short* Bsrc = B + (size_t)bcol * BN * DIM;

    f32x4 acc[8][4];
#pragma unroll
    for (int m = 0; m < 8; m++)
#pragma unroll
        for (int n = 0; n < 4; n++) acc[m][n] = (f32x4){0.f, 0.f, 0.f, 0.f};

    // ---- prologue: 7 chunks; vmcnt(8) confirms (0,B0),(0,B1),(0,A0) ----
    stage_chunk(0, 0, Asrc, Bsrc, smem, j0, laneoff);
    stage_chunk(1, 0, Asrc, Bsrc, smem, j0, laneoff);
    stage_chunk(2, 0, Asrc, Bsrc, smem, j0, laneoff);
    stage_chunk(3, 0, Asrc, Bsrc, smem, j0, laneoff);
    stage_chunk(0, 1, Asrc, Bsrc, smem, j0, laneoff);
    stage_chunk(1, 1, Asrc, Bsrc, smem, j0, laneoff);
    stage_chunk(2, 1, Asrc, Bsrc, smem, j0, laneoff);
    asm volatile("s_waitcnt vmcnt(8)" ::: "memory");
    __builtin_amdgcn_s_barrier();
    __builtin_amdgcn_sched_barrier(0);

    s16x8 bfr[4][2];

    for (int t = 0; t < NT; ++t) {
        const int b = t & 1;
        unsigned char* A_rd = smem + b * 32768;
        unsigned char* B_rd = smem + 65536 + b * 32768;

        // ---------------- window 0: acc[0..3] ----------------
        {
            s16x8 afr[4][2];
#pragma unroll
            for (int n = 0; n < 4; n++) {
                bfr[n][0] = LDBF(n, 0);
                bfr[n][1] = LDBF(n, 1);
            }
#pragma unroll
            for (int m = 0; m < 4; m++) {
                afr[m][0] = LDAF(m, 0);
                afr[m][1] = LDAF(m, 1);
            }
            stage_chunk(3, t + 1, Asrc, Bsrc, smem, j0, laneoff);  // (t+1,A1)
            __builtin_amdgcn_s_setprio(1);
#pragma unroll
            for (int kk = 0; kk < 2; kk++)
#pragma unroll
                for (int m = 0; m < 4; m++)
#pragma unroll
                    for (int n = 0; n < 4; n++)
                        acc[m][n] = __builtin_amdgcn_mfma_f32_16x16x32_bf16(
                            afr[m][kk], bfr[n][kk], acc[m][n], 0, 0, 0);
            __builtin_amdgcn_s_setprio(0);
            asm volatile("s_waitcnt vmcnt(8)" ::: "memory");
            __builtin_amdgcn_s_barrier();
            __builtin_amdgcn_sched_barrier(0);
        }
        // ---------------- window 1: acc[4..7] ----------------
        {
            s16x8 afr[4][2];
#pragma unroll
            for (int m = 0; m < 4; m++) {
                afr[m][0] = LDAF(m + 4, 0);
                afr[m][1] = LDAF(m + 4, 1);
            }
            stage_chunk(0, t + 2, Asrc, Bsrc, smem, j0, laneoff);  // (t+2,B0)
            stage_chunk(1, t + 2, Asrc, Bsrc, smem, j0, laneoff);  // (t+2,B1)
            stage_chunk(2, t + 2, Asrc, Bsrc, smem, j0, laneoff);  // (t+2,A0)
            __builtin_amdgcn_s_setprio(1);
#pragma unroll
            for (int kk = 0; kk < 2; kk++)
#pragma unroll
                for (int m = 0; m < 4; m++)
#pragma unroll
                    for (int n = 0; n < 4; n++)
                        acc[m + 4][n] = __builtin_amdgcn_mfma_f32_16x16x32_bf16(
                            afr[m][kk], bfr[n][kk], acc[m + 4][n], 0, 0, 0);
            __builtin_amdgcn_s_setprio(0);
            asm volatile("s_waitcnt vmcnt(8)" ::: "memory");
            __builtin_amdgcn_s_barrier();
            __builtin_amdgcn_sched_barrier(0);
        }
    }

    // ---- epilogue: per-row (sum_exp, sum_logit) over 256 columns ----
    // softcap bounds values to +-20 -> exp never overflows; no max needed.
    __syncthreads();   // full drain (also retires dummy wrap prefetches)
    float* red = (float*)(smem + 32768);   // [8][128][2] f32, aliases A buf1

#pragma unroll
    for (int m = 0; m < 8; m++) {
#pragma unroll
        for (int r = 0; r < 4; r++) {
            float s0 = softcap(acc[m][0][r]);
            float s1 = softcap(acc[m][1][r]);
            float s2 = softcap(acc[m][2][r]);
            float s3 = softcap(acc[m][3][r]);
            float se = __expf(s0) + __expf(s1) + __expf(s2) + __expf(s3);
            float st = s0 + s1 + s2 + s3;
#pragma unroll
            for (int off = 1; off < 16; off <<= 1) {
                se += __shfl_xor(se, off, 64);
                st += __shfl_xor(st, off, 64);
            }
            if (li == 0) {
                int rl = m * 16 + g * 4 + r;          // row within wave's 128
                int base = ((wr * 4 + wc) * 128 + rl) * 2;
                red[base + 0] = se;
                red[base + 1] = st;
            }
        }
    }
    __syncthreads();
    if (t0 < BM) {
        int r   = t0;
        int wr2 = r >> 7;
        int rr  = r & 127;
        float se = 0.f, st = 0.f;
#pragma unroll
        for (int q = 0; q < 4; q++) {
            int bq = ((wr2 * 4 + q) * 128 + rr) * 2;
            se += red[bq + 0];
            st += red[bq + 1];
        }
        part[(size_t)(brow * BM + r) * NCB + bcol] = make_float2(se, st);
    }
}

// ---------------------------------------------------------------------------
// K1 fallback (small ws): reg-staged f32->bf16, 128x128, BK=32.
// ---------------------------------------------------------------------------
__global__ __launch_bounds__(256) void gemm_partial_f32(
    const float* __restrict__ hidden, const float* __restrict__ weight,
    float2* __restrict__ part)
{
    __shared__ unsigned short sA[128 * 32];
    __shared__ unsigned short sB[128 * 32];
    __shared__ float red[4][64][2];

    const int bid  = blockIdx.x;
    const int brow = bid & 31;
    const int bcol = bid >> 5;
    const int t    = threadIdx.x;
    const int lane = t & 63;
    const int w    = t >> 6;
    const int wr   = w >> 1, wc = w & 1;

    const int srow = t >> 1;
    const int scol = (t & 1) * 16;
    const float* gA = hidden + (size_t)(brow * 128 + srow) * DIM + scol;
    const float* gB = weight + (size_t)(bcol * 128 + srow) * DIM + scol;
    unsigned short* wA = &sA[srow * 32 + scol];
    unsigned short* wB = &sB[srow * 32 + scol];

    f32x4 acc[4][4];
#pragma unroll
    for (int m = 0; m < 4; m++)
#pragma unroll
        for (int n = 0; n < 4; n++) acc[m][n] = (f32x4){0.f, 0.f, 0.f, 0.f};

    const unsigned short* pa = &sA[(wr * 64 + (lane & 15)) * 32 + (lane >> 4) * 8];
    const unsigned short* pb = &sB[(wc * 64 + (lane & 15)) * 32 + (lane >> 4) * 8];

    for (int k0 = 0; k0 < DIM; k0 += 32) {
        float4 a0 = *(const float4*)(gA + k0);
        float4 a1 = *(const float4*)(gA + k0 + 4);
        float4 a2 = *(const float4*)(gA + k0 + 8);
        float4 a3 = *(const float4*)(gA + k0 + 12);
        float4 b0 = *(const float4*)(gB + k0);
        float4 b1 = *(const float4*)(gB + k0 + 4);
        float4 b2 = *(const float4*)(gB + k0 + 8);
        float4 b3 = *(const float4*)(gB + k0 + 12);
        __syncthreads();
        u16x8 pa0 = { f2bf(a0.x), f2bf(a0.y), f2bf(a0.z), f2bf(a0.w),
                      f2bf(a1.x), f2bf(a1.y), f2bf(a1.z), f2bf(a1.w) };
        u16x8 pa1 = { f2bf(a2.x), f2bf(a2.y), f2bf(a2.z), f2bf(a2.w),
                      f2bf(a3.x), f2bf(a3.y), f2bf(a3.z), f2bf(a3.w) };
        u16x8 pb0 = { f2bf(b0.x), f2bf(b0.y), f2bf(b0.z), f2bf(b0.w),
                      f2bf(b1.x), f2bf(b1.y), f2bf(b1.z), f2bf(b1.w) };
        u16x8 pb1 = { f2bf(b2.x), f2bf(b2.y), f2bf(b2.z), f2bf(b2.w),
                      f2bf(b3.x), f2bf(b3.y), f2bf(b3.z), f2bf(b3.w) };
        *(u16x8*)wA = pa0;
        *(u16x8*)(wA + 8) = pa1;
        *(u16x8*)wB = pb0;
        *(u16x8*)(wB + 8) = pb1;
        __syncthreads();

        s16x8 afr[4], bfr[4];
#pragma unroll
        for (int m = 0; m < 4; m++) afr[m] = *(const s16x8*)(pa + m * 16 * 32);
#pragma unroll
        for (int n = 0; n < 4; n++) bfr[n] = *(const s16x8*)(pb + n * 16 * 32);
#pragma unroll
        for (int m = 0; m < 4; m++)
#pragma unroll
            for (int n = 0; n < 4; n++)
                acc[m][n] = __builtin_amdgcn_mfma_f32_16x16x32_bf16(
                    afr[m], bfr[n], acc[m][n], 0, 0, 0);
    }

    const int g  = lane >> 4;
    const int li = lane & 15;
#pragma unroll
    for (int m = 0; m < 4; m++) {
#pragma unroll
        for (int r = 0; r < 4; r++) {
            float s0 = softcap(acc[m][0][r]);
            float s1 = softcap(acc[m][1][r]);
            float s2 = softcap(acc[m][2][r]);
            float s3 = softcap(acc[m][3][r]);
            float se = __expf(s0) + __expf(s1) + __expf(s2) + __expf(s3);
            float st = s0 + s1 + s2 + s3;
#pragma unroll
            for (int off = 1; off < 16; off <<= 1) {
                se += __shfl_xor(se, off, 64);
                st += __shfl_xor(st, off, 64);
            }
            if (li == 0) {
                int rl = m * 16 + g * 4 + r;
                red[w][rl][0] = se;
                red[w][rl][1] = st;
            }
        }
    }
    __syncthreads();
    if (t < 128) {
        int r  = t;
        int wa = (r >> 6) * 2;
        int rr = r & 63;
        float se = red[wa][rr][0] + red[wa + 1][rr][0];
        float st = red[wa][rr][1] + red[wa + 1][rr][1];
        part[(size_t)(brow * 128 + r) * 256 + bcol] = make_float2(se, st);
    }
}

// ---------------------------------------------------------------------------
// K2: sum ncb column-block partials per row. 1 wave/row.
// ---------------------------------------------------------------------------
__global__ __launch_bounds__(256) void row_reduce(
    const float2* __restrict__ part, const int* __restrict__ targets,
    const float* __restrict__ xtbuf, float* __restrict__ rowbuf, int ncb)
{
    int row  = blockIdx.x * 4 + (threadIdx.x >> 6);
    int lane = threadIdx.x & 63;
    if (row >= N_ROWS) return;
    const float2* p = part + (size_t)row * ncb;
    float se = 0.f, st = 0.f;
    for (int q = lane; q < ncb; q += 64) {
        float2 u = p[q];
        se += u.x;
        st += u.y;
    }
#pragma unroll
    for (int off = 1; off < 64; off <<= 1) {
        se += __shfl_xor(se, off, 64);
        st += __shfl_xor(st, off, 64);
    }
    if (lane == 0) {
        float lse = logf(se);
        int   tgt = targets[row];
        float vf  = (tgt != IGNORE_IDX) ? 1.f : 0.f;
        float xt  = xtbuf[row];
        float nll = lse - xt;
        float smooth = lse - st * (1.f / (float)VOCAB);
        float rl = 0.9f * nll + 0.1f * smooth;
        rowbuf[row * 3 + 0] = rl * vf;
        rowbuf[row * 3 + 1] = lse * lse * vf;
        rowbuf[row * 3 + 2] = vf;
    }
}

// ---------------------------------------------------------------------------
// K3: deterministic final reduction -> scalar loss.
// ---------------------------------------------------------------------------
__global__ __launch_bounds__(256) void final_reduce(
    const float* __restrict__ rowbuf, float* __restrict__ out)
{
    __shared__ float sl[256], sz[256], sv[256];
    int t = threadIdx.x;
    float ls = 0.f, zs = 0.f, vs = 0.f;
    for (int r = t; r < N_ROWS; r += 256) {
        ls += rowbuf[r * 3 + 0];
        zs += rowbuf[r * 3 + 1];
        vs += rowbuf[r * 3 + 2];
    }
    sl[t] = ls; sz[t] = zs; sv[t] = vs;
    __syncthreads();
    for (int o = 128; o > 0; o >>= 1) {
        if (t < o) { sl[t] += sl[t + o]; sz[t] += sz[t + o]; sv[t] += sv[t + o]; }
        __syncthreads();
    }
    if (t == 0) {
        float nv = fmaxf(sv[0], 1.f);
        out[0] = sl[0] / nv + 1e-4f * (sz[0] / nv);
    }
}

// ---------------------------------------------------------------------------
extern "C" void kernel_launch(void* const* d_in, const int* in_sizes, int n_in,
                              void* d_out, int out_size, void* d_ws, size_t ws_size,
                              hipStream_t stream)
{
    const float* hidden  = (const float*)d_in[0];
    const float* weight  = (const float*)d_in[1];
    const int*   targets = (const int*)d_in[2];
    float*       out     = (float*)d_out;

    char* ws = (char*)d_ws;
    size_t off = 0;
    float2* part = (float2*)(ws + off);
    off += (size_t)N_ROWS * 256 * sizeof(float4);           // 16 MB slot (max layout)
    float* xtbuf = (float*)(ws + off);
    off += (size_t)N_ROWS * sizeof(float);
    float* rowbuf = (float*)(ws + off);
    off += (size_t)N_ROWS * 3 * sizeof(float);
    off = (off + 255) & ~(size_t)255;
    unsigned short* hidB = (unsigned short*)(ws + off);
    off += (size_t)N_ROWS * DIM * sizeof(unsigned short);   // 16 MB
    unsigned short* wgtB = (unsigned short*)(ws + off);
    off += (size_t)VOCAB * DIM * sizeof(unsigned short);    // 134 MB

    target_logit<<<N_ROWS / 4, 256, 0, stream>>>(hidden, weight, targets, xtbuf);

    if (ws_size >= off) {
        convert_bf16<<<2048, 256, 0, stream>>>(hidden, hidB, N_ROWS * DIM / 8);
        convert_bf16<<<2048, 256, 0, stream>>>(weight, wgtB, VOCAB * DIM / 8);
        gemm8ph<<<ROW_TILES * (VOCAB / BN), 512, 0, stream>>>(hidB, wgtB, part);
        row_reduce<<<N_ROWS / 4, 256, 0, stream>>>(part, targets, xtbuf, rowbuf, NCB);
    } else {
        gemm_partial_f32<<<32 * 256, 256, 0, stream>>>(hidden, weight, part);
        row_reduce<<<N_ROWS / 4, 256, 0, stream>>>(part, targets, xtbuf, rowbuf, 256);
    }

    final_reduce<<<1, 256, 0, stream>>>(rowbuf, out);
}